// Round 1
// baseline (2848.171 us; speedup 1.0000x reference)
//
#include <hip/hip_runtime.h>

typedef unsigned short u16;
typedef __attribute__((ext_vector_type(4))) float f32x4;
typedef __attribute__((ext_vector_type(8))) __bf16 bf16x8;
typedef __attribute__((ext_vector_type(4))) unsigned short u16x4;

static __device__ __forceinline__ u16 f2bf(float f) {
  union { float f; unsigned u; } v; v.f = f;
  unsigned r = v.u + 0x7fffu + ((v.u >> 16) & 1u);
  return (u16)(r >> 16);
}

#define GLD_LDS(g, l) __builtin_amdgcn_global_load_lds( \
    (const __attribute__((address_space(1))) void*)(g), \
    (__attribute__((address_space(3))) void*)(l), 16, 0, 0)

// C = A[M,K] @ Bt[N,K]^T, bf16 inputs, f32 accum. 128x128 tile, BK=32, 4 waves.
// EPI: 0 = Cf = alpha*acc + bias; 1 = Cf += acc + bias; 2 = Cb = bf16(acc+bias);
//      3 = Cb = bf16(relu(acc+bias))
template<int EPI>
__global__ __launch_bounds__(256)
void gemm_bt(const u16* __restrict__ A, const u16* __restrict__ B,
             float* __restrict__ Cf, u16* __restrict__ Cb,
             const float* __restrict__ bias, float alpha,
             int K, int lda, int ldb, int ldc,
             long long sA, long long sB, long long sC)
{
  __shared__ u16 ldsA[128 * 32];
  __shared__ u16 ldsB[128 * 32];
  const int t = threadIdx.x;
  const int w = t >> 6, l = t & 63;
  const long long bz = blockIdx.z;
  const int m0 = blockIdx.y << 7, n0 = blockIdx.x << 7;
  const u16* Ab = A + bz * sA;
  const u16* Bb = B + bz * sB;
  const int wr = (w >> 1) << 6, wc = (w & 1) << 6;
  const int l15 = l & 15, l16 = l >> 4;
  f32x4 acc[4][4] = {};

  for (int k0 = 0; k0 < K; k0 += 32) {
#pragma unroll
    for (int r = 0; r < 2; ++r) {
      const int o = (r << 12) + (t << 4);   // byte offset within the 8 KB tile
      const int row = o >> 6;               // 64 B per tile row (32 bf16)
      const int cole = (o & 63) >> 1;       // element col within BK
      GLD_LDS(Ab + (long long)(m0 + row) * lda + k0 + cole, &ldsA[(r << 11) + (w << 9)]);
      GLD_LDS(Bb + (long long)(n0 + row) * ldb + k0 + cole, &ldsB[(r << 11) + (w << 9)]);
    }
    __syncthreads();
    bf16x8 af[4], bg[4];
#pragma unroll
    for (int i = 0; i < 4; ++i) {
      af[i] = *(const bf16x8*)&ldsA[(wr + i * 16 + l15) * 32 + l16 * 8];
      bg[i] = *(const bf16x8*)&ldsB[(wc + i * 16 + l15) * 32 + l16 * 8];
    }
#pragma unroll
    for (int i = 0; i < 4; ++i)
#pragma unroll
      for (int j = 0; j < 4; ++j)
        acc[i][j] = __builtin_amdgcn_mfma_f32_16x16x32_bf16(af[i], bg[j], acc[i][j], 0, 0, 0);
    __syncthreads();
  }

#pragma unroll
  for (int i = 0; i < 4; ++i) {
    const int rbase = m0 + wr + i * 16 + l16 * 4;
#pragma unroll
    for (int j = 0; j < 4; ++j) {
      const int col = n0 + wc + j * 16 + l15;
      const float bv = bias ? bias[col] : 0.f;
#pragma unroll
      for (int r = 0; r < 4; ++r) {
        const long long idx = bz * sC + (long long)(rbase + r) * ldc + col;
        const float v = acc[i][j][r];
        if (EPI == 0)      Cf[idx] = alpha * v + bv;
        else if (EPI == 1) Cf[idx] += v + bv;
        else if (EPI == 2) Cb[idx] = f2bf(v + bv);
        else               { float x = v + bv; Cb[idx] = f2bf(x > 0.f ? x : 0.f); }
      }
    }
  }
}

// LayerNorm over rows of 1024 f32 -> bf16 out
__global__ __launch_bounds__(256)
void ln_k(const float* __restrict__ x, const float* __restrict__ g,
          const float* __restrict__ b, u16* __restrict__ z)
{
  const long long row = blockIdx.x;
  f32x4 v = ((const f32x4*)(x + row * 1024))[threadIdx.x];
  float s = v[0] + v[1] + v[2] + v[3];
  float q = v[0] * v[0] + v[1] * v[1] + v[2] * v[2] + v[3] * v[3];
#pragma unroll
  for (int o = 32; o; o >>= 1) { s += __shfl_down(s, o); q += __shfl_down(q, o); }
  __shared__ float rs_[4], rq_[4];
  const int l = threadIdx.x & 63, w = threadIdx.x >> 6;
  if (l == 0) { rs_[w] = s; rq_[w] = q; }
  __syncthreads();
  s = rs_[0] + rs_[1] + rs_[2] + rs_[3];
  q = rq_[0] + rq_[1] + rq_[2] + rq_[3];
  const float mu = s * (1.f / 1024.f);
  const float rstd = rsqrtf(q * (1.f / 1024.f) - mu * mu + 1e-5f);
  const f32x4 gv = ((const f32x4*)g)[threadIdx.x];
  const f32x4 bv = ((const f32x4*)b)[threadIdx.x];
  u16x4 o4;
#pragma unroll
  for (int e = 0; e < 4; ++e) o4[e] = f2bf((v[e] - mu) * rstd * gv[e] + bv[e]);
  ((u16x4*)(z + row * 1024))[threadIdx.x] = o4;
}

// row softmax over 2048 f32 -> bf16
__global__ __launch_bounds__(256)
void softmax_k(const float* __restrict__ S, u16* __restrict__ P)
{
  const long long row = blockIdx.x;
  const f32x4* sr = (const f32x4*)(S + row * 2048);
  f32x4 v0 = sr[threadIdx.x], v1 = sr[threadIdx.x + 256];
  float m = v0[0];
#pragma unroll
  for (int e = 1; e < 4; ++e) m = fmaxf(m, v0[e]);
#pragma unroll
  for (int e = 0; e < 4; ++e) m = fmaxf(m, v1[e]);
#pragma unroll
  for (int o = 32; o; o >>= 1) m = fmaxf(m, __shfl_down(m, o));
  __shared__ float rm[4], rs[4];
  const int l = threadIdx.x & 63, w = threadIdx.x >> 6;
  if (l == 0) rm[w] = m;
  __syncthreads();
  m = fmaxf(fmaxf(rm[0], rm[1]), fmaxf(rm[2], rm[3]));
  float e0[4], e1[4], s = 0.f;
#pragma unroll
  for (int e = 0; e < 4; ++e) { e0[e] = __expf(v0[e] - m); s += e0[e]; }
#pragma unroll
  for (int e = 0; e < 4; ++e) { e1[e] = __expf(v1[e] - m); s += e1[e]; }
#pragma unroll
  for (int o = 32; o; o >>= 1) s += __shfl_down(s, o);
  if (l == 0) rs[w] = s;
  __syncthreads();
  s = rs[0] + rs[1] + rs[2] + rs[3];
  const float inv = 1.f / s;
  u16x4 o0, o1;
#pragma unroll
  for (int e = 0; e < 4; ++e) { o0[e] = f2bf(e0[e] * inv); o1[e] = f2bf(e1[e] * inv); }
  ((u16x4*)(P + row * 2048))[threadIdx.x] = o0;
  ((u16x4*)(P + row * 2048))[threadIdx.x + 256] = o1;
}

__global__ __launch_bounds__(256)
void gather_k(const int* __restrict__ x, const float* __restrict__ emb, float* __restrict__ h)
{
  const long long tok = blockIdx.x;
  const long long r = (long long)x[tok] << 8;   // float4 units per row = 256
  ((f32x4*)h)[(tok << 8) + threadIdx.x] = ((const f32x4*)emb)[r + threadIdx.x];
}

__global__ __launch_bounds__(256)
void cast_k(const float* __restrict__ h, u16* __restrict__ o)
{
  const long long i = (long long)blockIdx.x * 256 + threadIdx.x;
  f32x4 v = ((const f32x4*)h)[i];
  u16x4 u;
#pragma unroll
  for (int e = 0; e < 4; ++e) u[e] = f2bf(v[e]);
  ((u16x4*)o)[i] = u;
}

// f32 [R][C] -> bf16 [C][R]
__global__ __launch_bounds__(256)
void tcast_k(const float* __restrict__ in, u16* __restrict__ out, int R, int C)
{
  __shared__ float tile[32][33];
  const int tx = threadIdx.x & 31, ty = threadIdx.x >> 5;
  const long long r0 = (long long)blockIdx.y << 5, c0 = (long long)blockIdx.x << 5;
#pragma unroll
  for (int yy = 0; yy < 32; yy += 8)
    tile[ty + yy][tx] = in[(r0 + ty + yy) * C + c0 + tx];
  __syncthreads();
#pragma unroll
  for (int yy = 0; yy < 32; yy += 8)
    out[(c0 + ty + yy) * R + r0 + tx] = f2bf(tile[tx][ty + yy]);
}

// fused QKV weight, transposed+padded: out[n][e], n in [0,256)
__global__ __launch_bounds__(256)
void wqkv_k(const float* __restrict__ Wq, const float* __restrict__ Wk,
            const float* __restrict__ Wv, u16* __restrict__ o)
{
  const int n = blockIdx.y;
  const long long e = (long long)blockIdx.x * 256 + threadIdx.x;
  float v = 0.f;
  if (n < 64)       v = Wq[e * 64 + n];
  else if (n < 128) v = Wk[e * 64 + (n - 64)];
  else if (n < 192) v = Wv[e * 64 + (n - 128)];
  o[(long long)n * 1024 + e] = f2bf(v);
}

__global__ __launch_bounds__(256)
void bqkv_k(const float* __restrict__ bq, const float* __restrict__ bk,
            const float* __restrict__ bv, float* __restrict__ o)
{
  const int n = threadIdx.x;
  float v = 0.f;
  if (n < 64)       v = bq[n];
  else if (n < 128) v = bk[n - 64];
  else if (n < 192) v = bv[n - 128];
  o[n] = v;
}

// Wdsum_t[e][a] = bf16( sum_h Wd[h*64+a][e] )   (i = e*64+a)
__global__ __launch_bounds__(256)
void wdsum_k(const float* __restrict__ Wd, u16* __restrict__ o)
{
  const int i = blockIdx.x * 256 + threadIdx.x;
  const int a = i & 63, e = i >> 6;
  float s = 0.f;
#pragma unroll
  for (int hh = 0; hh < 16; ++hh) s += Wd[(long long)(hh * 64 + a) * 1024 + e];
  o[i] = f2bf(s);
}

// vT[b][a][s] (a padded to 128 with zeros), v = qkv cols [128,192)
__global__ __launch_bounds__(256)
void vt_k(const u16* __restrict__ qkv, u16* __restrict__ vT)
{
  const int s = blockIdx.x * 256 + threadIdx.x;
  const int a = blockIdx.y;
  const int b = blockIdx.z;
  u16 v = 0;
  if (a < 64) v = qkv[((long long)(b * 2048 + s)) * 256 + 128 + a];
  vT[((long long)(b * 128 + a)) * 2048 + s] = v;
}

extern "C" void kernel_launch(void* const* d_in, const int* in_sizes, int n_in,
                              void* d_out, int out_size, void* d_ws, size_t ws_size,
                              hipStream_t stream) {
  const int*   x   = (const int*)d_in[0];
  const float* emb = (const float*)d_in[1];
  const float* Wq  = (const float*)d_in[2];
  const float* bq  = (const float*)d_in[3];
  const float* Wk  = (const float*)d_in[4];
  const float* bk  = (const float*)d_in[5];
  const float* Wv  = (const float*)d_in[6];
  const float* bv  = (const float*)d_in[7];
  const float* Wd  = (const float*)d_in[8];
  const float* bd  = (const float*)d_in[9];
  const float* g1  = (const float*)d_in[10];
  const float* be1 = (const float*)d_in[11];
  const float* g2  = (const float*)d_in[12];
  const float* be2 = (const float*)d_in[13];
  const float* W1  = (const float*)d_in[14];
  const float* c1  = (const float*)d_in[15];
  const float* W2  = (const float*)d_in[16];
  const float* c2  = (const float*)d_in[17];
  const float* Wfc = (const float*)d_in[18];
  const float* bfc = (const float*)d_in[19];
  float* out = (float*)d_out;

  char* ws = (char*)d_ws;
  size_t off = 0;
  auto alloc = [&](size_t bytes) { void* p = ws + off; off = (off + bytes + 255) & ~(size_t)255; return p; };
  float*  h     = (float*) alloc(4096ull * 1024 * 4);
  u16*    z     = (u16*)   alloc(4096ull * 1024 * 2);   // reused: z1, z2, hb
  u16*    qkv   = (u16*)   alloc(4096ull * 256 * 2);
  u16*    vT    = (u16*)   alloc(2ull * 128 * 2048 * 2);
  float*  sc    = (float*) alloc(2ull * 2048 * 2048 * 4);
  u16*    P     = (u16*)   alloc(2ull * 2048 * 2048 * 2);
  u16*    head  = (u16*)   alloc(2ull * 2048 * 128 * 2);
  u16*    mid   = (u16*)   alloc(4096ull * 4096 * 2);
  u16*    Wqkvt = (u16*)   alloc(256ull * 1024 * 2);
  float*  bqkv  = (float*) alloc(256 * 4);
  u16*    Wdst  = (u16*)   alloc(1024ull * 64 * 2);
  u16*    W1t   = (u16*)   alloc(4096ull * 1024 * 2);
  u16*    W2t   = (u16*)   alloc(1024ull * 4096 * 2);
  u16*    Wfct  = (u16*)   alloc(32000ull * 1024 * 2);

  // ---- prep (runs every launch; no caching allowed) ----
  gather_k<<<4096, 256, 0, stream>>>(x, emb, h);
  wqkv_k<<<dim3(4, 256), 256, 0, stream>>>(Wq, Wk, Wv, Wqkvt);
  bqkv_k<<<1, 256, 0, stream>>>(bq, bk, bv, bqkv);
  wdsum_k<<<256, 256, 0, stream>>>(Wd, Wdst);
  tcast_k<<<dim3(128, 32), 256, 0, stream>>>(W1, W1t, 1024, 4096);
  tcast_k<<<dim3(32, 128), 256, 0, stream>>>(W2, W2t, 4096, 1024);
  tcast_k<<<dim3(1000, 32), 256, 0, stream>>>(Wfc, Wfct, 1024, 32000);

  for (int layer = 0; layer < 8; ++layer) {
    ln_k<<<4096, 256, 0, stream>>>(h, g1, be1, z);
    // qkv[4096,256] = z @ Wqkv^T + bias  (bf16 out)
    gemm_bt<2><<<dim3(2, 32, 1), 256, 0, stream>>>(z, Wqkvt, nullptr, qkv, bqkv, 1.f,
        1024, 1024, 1024, 256, 0, 0, 0);
    vt_k<<<dim3(8, 128, 2), 256, 0, stream>>>(qkv, vT);
    // scores[b,2048,2048] = 0.125 * q @ k^T
    gemm_bt<0><<<dim3(16, 16, 2), 256, 0, stream>>>(qkv, qkv + 64, sc, nullptr, nullptr, 0.125f,
        64, 256, 256, 2048, 2048ll * 256, 2048ll * 256, 2048ll * 2048);
    softmax_k<<<4096, 256, 0, stream>>>(sc, P);
    // head[b,2048,128] = P @ vT^T (bf16)
    gemm_bt<2><<<dim3(1, 16, 2), 256, 0, stream>>>(P, vT, nullptr, head, nullptr, 1.f,
        2048, 2048, 2048, 128, 2048ll * 2048, 128ll * 2048, 2048ll * 128);
    // h += head @ Wdsum^T + bd
    gemm_bt<1><<<dim3(8, 32, 1), 256, 0, stream>>>(head, Wdst, h, nullptr, bd, 1.f,
        64, 128, 64, 1024, 0, 0, 0);
    ln_k<<<4096, 256, 0, stream>>>(h, g2, be2, z);
    // mid = relu(z2 @ W1 + c1) (bf16)
    gemm_bt<3><<<dim3(32, 32, 1), 256, 0, stream>>>(z, W1t, nullptr, mid, c1, 1.f,
        1024, 1024, 1024, 4096, 0, 0, 0);
    // h += mid @ W2 + c2
    gemm_bt<1><<<dim3(8, 32, 1), 256, 0, stream>>>(mid, W2t, h, nullptr, c2, 1.f,
        4096, 4096, 4096, 1024, 0, 0, 0);
  }
  cast_k<<<4096, 256, 0, stream>>>(h, z);
  // out[4096,32000] = hb @ Wfc + bfc
  gemm_bt<0><<<dim3(250, 32, 1), 256, 0, stream>>>(z, Wfct, out, nullptr, bfc, 1.f,
      1024, 1024, 1024, 32000, 0, 0, 0);
}

// Round 2
// 2414.548 us; speedup vs baseline: 1.1796x; 1.1796x over previous
//
#include <hip/hip_runtime.h>

typedef unsigned short u16;
typedef __attribute__((ext_vector_type(4))) float f32x4;
typedef __attribute__((ext_vector_type(8))) __bf16 bf16x8;
typedef __attribute__((ext_vector_type(4))) unsigned short u16x4;

static __device__ __forceinline__ u16 f2bf(float f) {
  union { float f; unsigned u; } v; v.f = f;
  unsigned r = v.u + 0x7fffu + ((v.u >> 16) & 1u);
  return (u16)(r >> 16);
}

#define GLD_LDS(g, l) __builtin_amdgcn_global_load_lds( \
    (const __attribute__((address_space(1))) void*)(g), \
    (__attribute__((address_space(3))) void*)(l), 16, 0, 0)

// C = A[M,K] @ Bt[N,K]^T, bf16 in, f32 accum. 128x128 tile, BK=32, 4 waves.
// Grid: x = mtiles*ntiles (flattened, XCD-swizzled, M-major for B-panel reuse), z = batch*nsplit+sp.
// A += batch*sA + sp*K ; B += batch*sB + sp*K ; C base = blockIdx.z * sC (per-z stride).
// EPI: 0 = Cf = alpha*acc + bias; 1 = Cf += acc + bias; 2 = Cb = bf16(acc+bias);
//      3 = Cb = bf16(relu(acc+bias))
template<int EPI>
__global__ __launch_bounds__(256)
void gemm_bt(const u16* __restrict__ A, const u16* __restrict__ B,
             float* __restrict__ Cf, u16* __restrict__ Cb,
             const float* __restrict__ bias, float alpha,
             int K, int lda, int ldb, int ldc, int mtiles, int nsplit,
             long long sA, long long sB, long long sC)
{
  __shared__ u16 ldsA[128 * 32];
  __shared__ u16 ldsB[128 * 32];
  const int t = threadIdx.x;
  const int w = t >> 6, l = t & 63;

  // bijective XCD chunk swizzle (m204) + M-major tile order
  int wg = blockIdx.x;
  const int nwg = gridDim.x;
  {
    const int q = nwg >> 3, r = nwg & 7;
    const int xcd = wg & 7, loc = wg >> 3;
    wg = (xcd < r ? xcd * (q + 1) : r * (q + 1) + (xcd - r) * q) + loc;
  }
  const int mt = wg % mtiles, nt = wg / mtiles;
  const int m0 = mt << 7, n0 = nt << 7;

  const int bzRaw = blockIdx.z;
  int batch = bzRaw, sp = 0;
  if (nsplit > 1) { batch = bzRaw / nsplit; sp = bzRaw - batch * nsplit; }
  const u16* Ab = A + (long long)batch * sA + (long long)sp * K;
  const u16* Bb = B + (long long)batch * sB + (long long)sp * K;
  const long long cbase = (long long)bzRaw * sC;

  const int wr = (w >> 1) << 6, wc = (w & 1) << 6;
  const int l15 = l & 15, l16 = l >> 4;
  f32x4 acc[4][4] = {};

  for (int k0 = 0; k0 < K; k0 += 32) {
#pragma unroll
    for (int r = 0; r < 2; ++r) {
      const int o = (r << 12) + (t << 4);   // byte offset within the 8 KB tile
      const int row = o >> 6;               // 64 B per tile row (32 bf16)
      const int cole = (o & 63) >> 1;       // element col within BK
      GLD_LDS(Ab + (long long)(m0 + row) * lda + k0 + cole, &ldsA[(r << 11) + (w << 9)]);
      GLD_LDS(Bb + (long long)(n0 + row) * ldb + k0 + cole, &ldsB[(r << 11) + (w << 9)]);
    }
    __syncthreads();
    bf16x8 af[4], bg[4];
#pragma unroll
    for (int i = 0; i < 4; ++i) {
      af[i] = *(const bf16x8*)&ldsA[(wr + i * 16 + l15) * 32 + l16 * 8];
      bg[i] = *(const bf16x8*)&ldsB[(wc + i * 16 + l15) * 32 + l16 * 8];
    }
#pragma unroll
    for (int i = 0; i < 4; ++i)
#pragma unroll
      for (int j = 0; j < 4; ++j)
        acc[i][j] = __builtin_amdgcn_mfma_f32_16x16x32_bf16(af[i], bg[j], acc[i][j], 0, 0, 0);
    __syncthreads();
  }

#pragma unroll
  for (int i = 0; i < 4; ++i) {
    const int rbase = m0 + wr + i * 16 + l16 * 4;
#pragma unroll
    for (int j = 0; j < 4; ++j) {
      const int col = n0 + wc + j * 16 + l15;
      const float bv = bias ? bias[col] : 0.f;
#pragma unroll
      for (int r = 0; r < 4; ++r) {
        const long long idx = cbase + (long long)(rbase + r) * ldc + col;
        const float v = acc[i][j][r];
        if (EPI == 0)      Cf[idx] = alpha * v + bv;
        else if (EPI == 1) Cf[idx] += v + bv;
        else if (EPI == 2) Cb[idx] = f2bf(v + bv);
        else               { float x = v + bv; Cb[idx] = f2bf(x > 0.f ? x : 0.f); }
      }
    }
  }
}

// LayerNorm over rows of 1024 f32 -> bf16 out
__global__ __launch_bounds__(256)
void ln_k(const float* __restrict__ x, const float* __restrict__ g,
          const float* __restrict__ b, u16* __restrict__ z)
{
  const long long row = blockIdx.x;
  f32x4 v = ((const f32x4*)(x + row * 1024))[threadIdx.x];
  float s = v[0] + v[1] + v[2] + v[3];
  float q = v[0] * v[0] + v[1] * v[1] + v[2] * v[2] + v[3] * v[3];
#pragma unroll
  for (int o = 32; o; o >>= 1) { s += __shfl_down(s, o); q += __shfl_down(q, o); }
  __shared__ float rs_[4], rq_[4];
  const int l = threadIdx.x & 63, w = threadIdx.x >> 6;
  if (l == 0) { rs_[w] = s; rq_[w] = q; }
  __syncthreads();
  s = rs_[0] + rs_[1] + rs_[2] + rs_[3];
  q = rq_[0] + rq_[1] + rq_[2] + rq_[3];
  const float mu = s * (1.f / 1024.f);
  const float rstd = rsqrtf(q * (1.f / 1024.f) - mu * mu + 1e-5f);
  const f32x4 gv = ((const f32x4*)g)[threadIdx.x];
  const f32x4 bv = ((const f32x4*)b)[threadIdx.x];
  u16x4 o4;
#pragma unroll
  for (int e = 0; e < 4; ++e) o4[e] = f2bf((v[e] - mu) * rstd * gv[e] + bv[e]);
  ((u16x4*)(z + row * 1024))[threadIdx.x] = o4;
}

// row softmax over 2048 f32 -> bf16
__global__ __launch_bounds__(256)
void softmax_k(const float* __restrict__ S, u16* __restrict__ P)
{
  const long long row = blockIdx.x;
  const f32x4* sr = (const f32x4*)(S + row * 2048);
  f32x4 v0 = sr[threadIdx.x], v1 = sr[threadIdx.x + 256];
  float m = v0[0];
#pragma unroll
  for (int e = 1; e < 4; ++e) m = fmaxf(m, v0[e]);
#pragma unroll
  for (int e = 0; e < 4; ++e) m = fmaxf(m, v1[e]);
#pragma unroll
  for (int o = 32; o; o >>= 1) m = fmaxf(m, __shfl_down(m, o));
  __shared__ float rm[4], rs[4];
  const int l = threadIdx.x & 63, w = threadIdx.x >> 6;
  if (l == 0) rm[w] = m;
  __syncthreads();
  m = fmaxf(fmaxf(rm[0], rm[1]), fmaxf(rm[2], rm[3]));
  float e0[4], e1[4], s = 0.f;
#pragma unroll
  for (int e = 0; e < 4; ++e) { e0[e] = __expf(v0[e] - m); s += e0[e]; }
#pragma unroll
  for (int e = 0; e < 4; ++e) { e1[e] = __expf(v1[e] - m); s += e1[e]; }
#pragma unroll
  for (int o = 32; o; o >>= 1) s += __shfl_down(s, o);
  if (l == 0) rs[w] = s;
  __syncthreads();
  s = rs[0] + rs[1] + rs[2] + rs[3];
  const float inv = 1.f / s;
  u16x4 o0, o1;
#pragma unroll
  for (int e = 0; e < 4; ++e) { o0[e] = f2bf(e0[e] * inv); o1[e] = f2bf(e1[e] * inv); }
  ((u16x4*)(P + row * 2048))[threadIdx.x] = o0;
  ((u16x4*)(P + row * 2048))[threadIdx.x + 256] = o1;
}

__global__ __launch_bounds__(256)
void gather_k(const int* __restrict__ x, const float* __restrict__ emb, float* __restrict__ h)
{
  const long long tok = blockIdx.x;
  const long long r = (long long)x[tok] << 8;   // float4 units per row = 256
  ((f32x4*)h)[(tok << 8) + threadIdx.x] = ((const f32x4*)emb)[r + threadIdx.x];
}

__global__ __launch_bounds__(256)
void cast_k(const float* __restrict__ h, u16* __restrict__ o)
{
  const long long i = (long long)blockIdx.x * 256 + threadIdx.x;
  f32x4 v = ((const f32x4*)h)[i];
  u16x4 u;
#pragma unroll
  for (int e = 0; e < 4; ++e) u[e] = f2bf(v[e]);
  ((u16x4*)o)[i] = u;
}

// f32 [R][C] -> bf16 [C][R]
__global__ __launch_bounds__(256)
void tcast_k(const float* __restrict__ in, u16* __restrict__ out, int R, int C)
{
  __shared__ float tile[32][33];
  const int tx = threadIdx.x & 31, ty = threadIdx.x >> 5;
  const long long r0 = (long long)blockIdx.y << 5, c0 = (long long)blockIdx.x << 5;
#pragma unroll
  for (int yy = 0; yy < 32; yy += 8)
    tile[ty + yy][tx] = in[(r0 + ty + yy) * C + c0 + tx];
  __syncthreads();
#pragma unroll
  for (int yy = 0; yy < 32; yy += 8)
    out[(c0 + ty + yy) * R + r0 + tx] = f2bf(tile[tx][ty + yy]);
}

// fused QKV weight, transposed+padded: out[n][e], n in [0,256)
__global__ __launch_bounds__(256)
void wqkv_k(const float* __restrict__ Wq, const float* __restrict__ Wk,
            const float* __restrict__ Wv, u16* __restrict__ o)
{
  const int n = blockIdx.y;
  const long long e = (long long)blockIdx.x * 256 + threadIdx.x;
  float v = 0.f;
  if (n < 64)       v = Wq[e * 64 + n];
  else if (n < 128) v = Wk[e * 64 + (n - 64)];
  else if (n < 192) v = Wv[e * 64 + (n - 128)];
  o[(long long)n * 1024 + e] = f2bf(v);
}

__global__ __launch_bounds__(256)
void bqkv_k(const float* __restrict__ bq, const float* __restrict__ bk,
            const float* __restrict__ bv, float* __restrict__ o)
{
  const int n = threadIdx.x;
  float v = 0.f;
  if (n < 64)       v = bq[n];
  else if (n < 128) v = bk[n - 64];
  else if (n < 192) v = bv[n - 128];
  o[n] = v;
}

// Wdsum_t[e][a] = bf16( sum_h Wd[h*64+a][e] )   (i = e*64+a)
__global__ __launch_bounds__(256)
void wdsum_k(const float* __restrict__ Wd, u16* __restrict__ o)
{
  const int i = blockIdx.x * 256 + threadIdx.x;
  const int a = i & 63, e = i >> 6;
  float s = 0.f;
#pragma unroll
  for (int hh = 0; hh < 16; ++hh) s += Wd[(long long)(hh * 64 + a) * 1024 + e];
  o[i] = f2bf(s);
}

// ---- split-K reduces ----

// h += p[0] + p[1] + c2  (4096x1024 f32, per-z stride 4096*1024)
__global__ __launch_bounds__(256)
void reduce_ffn2(const float* __restrict__ p, float* __restrict__ h, const float* __restrict__ bias)
{
  const long long i4 = (long long)blockIdx.x * 256 + threadIdx.x;  // f32x4 units
  const int c4 = (int)(i4 & 255);
  f32x4 s = ((const f32x4*)p)[i4] + ((const f32x4*)p)[i4 + 1048576]
          + ((const f32x4*)bias)[c4];
  ((f32x4*)h)[i4] += s;
}

// head = bf16(sum of 4 partials) ; p layout [b*4+sp][2048*128]
__global__ __launch_bounds__(256)
void reduce_pv(const float* __restrict__ p, u16* __restrict__ head)
{
  const long long i4 = (long long)blockIdx.x * 256 + threadIdx.x;  // total 131072
  const long long b = i4 >> 16, loc = i4 & 65535;
  const long long base = b * 4 * 65536 + loc;
  const f32x4* p4 = (const f32x4*)p;
  f32x4 s = p4[base] + p4[base + 65536] + p4[base + 2 * 65536] + p4[base + 3 * 65536];
  u16x4 o;
#pragma unroll
  for (int e = 0; e < 4; ++e) o[e] = f2bf(s[e]);
  ((u16x4*)head)[i4] = o;
}

// qkv = bf16(p0+p1+bqkv), plus vT scatter for v-cols [128,192)
__global__ __launch_bounds__(256)
void reduce_qkv(const float* __restrict__ p, const float* __restrict__ bqkv,
                u16* __restrict__ qkv, u16* __restrict__ vT)
{
  const long long i4 = (long long)blockIdx.x * 256 + threadIdx.x;  // total 262144
  const int c4 = (int)(i4 & 63);
  const long long row = i4 >> 6;
  f32x4 s = ((const f32x4*)p)[i4] + ((const f32x4*)p)[i4 + 262144]
          + ((const f32x4*)bqkv)[c4];
  u16x4 o;
#pragma unroll
  for (int e = 0; e < 4; ++e) o[e] = f2bf(s[e]);
  ((u16x4*)qkv)[i4] = o;
  if (c4 >= 32 && c4 < 48) {  // v columns 128..191
    const long long b = row >> 11, sidx = row & 2047;
#pragma unroll
    for (int e = 0; e < 4; ++e) {
      const int a = (c4 - 32) * 4 + e;
      vT[(b * 128 + a) * 2048 + sidx] = o[e];
    }
  }
}

extern "C" void kernel_launch(void* const* d_in, const int* in_sizes, int n_in,
                              void* d_out, int out_size, void* d_ws, size_t ws_size,
                              hipStream_t stream) {
  const int*   x   = (const int*)d_in[0];
  const float* emb = (const float*)d_in[1];
  const float* Wq  = (const float*)d_in[2];
  const float* bq  = (const float*)d_in[3];
  const float* Wk  = (const float*)d_in[4];
  const float* bk  = (const float*)d_in[5];
  const float* Wv  = (const float*)d_in[6];
  const float* bv  = (const float*)d_in[7];
  const float* Wd  = (const float*)d_in[8];
  const float* bd  = (const float*)d_in[9];
  const float* g1  = (const float*)d_in[10];
  const float* be1 = (const float*)d_in[11];
  const float* g2  = (const float*)d_in[12];
  const float* be2 = (const float*)d_in[13];
  const float* W1  = (const float*)d_in[14];
  const float* c1  = (const float*)d_in[15];
  const float* W2  = (const float*)d_in[16];
  const float* c2  = (const float*)d_in[17];
  const float* Wfc = (const float*)d_in[18];
  const float* bfc = (const float*)d_in[19];
  float* out = (float*)d_out;

  char* ws = (char*)d_ws;
  size_t off = 0;
  auto alloc = [&](size_t bytes) { void* p = ws + off; off = (off + bytes + 255) & ~(size_t)255; return p; };
  float*  h     = (float*) alloc(4096ull * 1024 * 4);
  u16*    z     = (u16*)   alloc(4096ull * 1024 * 2);   // z1/z2/hb (reused)
  u16*    qkv   = (u16*)   alloc(4096ull * 256 * 2);
  u16*    vT    = (u16*)   alloc(2ull * 128 * 2048 * 2);
  u16*    head  = (u16*)   alloc(2ull * 2048 * 128 * 2);
  u16*    mid   = (u16*)   alloc(4096ull * 4096 * 2);
  // scratch region with lifetime-based aliasing:
  //   partQ (8.4MB) [QKV gemm -> reduce]   at SCR+0
  //   sc    (33.5MB)[scores  -> softmax]   at SCR+0      (partQ dead)
  //   P     (16.8MB)[softmax -> PV gemm]   at SCR+33.5MB
  //   partH (8.4MB) [PV gemm -> reduce]    at SCR+0      (sc dead)
  //   partF (33.5MB)[FFN2    -> reduce]    at SCR+0      (P dead)
  char*   SCR   = (char*)  alloc(2ull * 2048 * 2048 * 4 + 2ull * 2048 * 2048 * 2);
  float*  sc    = (float*)SCR;
  float*  partQ = (float*)SCR;
  float*  partH = (float*)SCR;
  float*  partF = (float*)SCR;
  u16*    P     = (u16*)(SCR + 2ull * 2048 * 2048 * 4);
  u16*    Wqkvt = (u16*)   alloc(256ull * 1024 * 2);
  float*  bqkv  = (float*) alloc(256 * 4);
  u16*    Wdst  = (u16*)   alloc(1024ull * 64 * 2);
  u16*    W1t   = (u16*)   alloc(4096ull * 1024 * 2);
  u16*    W2t   = (u16*)   alloc(1024ull * 4096 * 2);
  u16*    Wfct  = (u16*)   alloc(32000ull * 1024 * 2);

  // ---- prep (every launch; no caching allowed) ----
  gather_k<<<4096, 256, 0, stream>>>(x, emb, h);
  wqkv_k<<<dim3(4, 256), 256, 0, stream>>>(Wq, Wk, Wv, Wqkvt);
  bqkv_k<<<1, 256, 0, stream>>>(bq, bk, bv, bqkv);
  wdsum_k<<<256, 256, 0, stream>>>(Wd, Wdst);
  tcast_k<<<dim3(128, 32), 256, 0, stream>>>(W1, W1t, 1024, 4096);
  tcast_k<<<dim3(32, 128), 256, 0, stream>>>(W2, W2t, 4096, 1024);
  tcast_k<<<dim3(1000, 32), 256, 0, stream>>>(Wfc, Wfct, 1024, 32000);

  for (int layer = 0; layer < 8; ++layer) {
    ln_k<<<4096, 256, 0, stream>>>(h, g1, be1, z);
    // partQ[z] = z1 @ Wqkv^T (split-K x2, K=512 each)
    gemm_bt<0><<<dim3(64, 1, 2), 256, 0, stream>>>(z, Wqkvt, partQ, nullptr, nullptr, 1.f,
        512, 1024, 1024, 256, 32, 2, 0, 0, 1048576);
    reduce_qkv<<<1024, 256, 0, stream>>>(partQ, bqkv, qkv, vT);
    // scores[b] = 0.125 * q @ k^T
    gemm_bt<0><<<dim3(256, 1, 2), 256, 0, stream>>>(qkv, qkv + 64, sc, nullptr, nullptr, 0.125f,
        64, 256, 256, 2048, 16, 1, 2048ll * 256, 2048ll * 256, 2048ll * 2048);
    softmax_k<<<4096, 256, 0, stream>>>(sc, P);
    // partH[b*4+sp] = P @ vT^T (split-K x4, K=512 each)
    gemm_bt<0><<<dim3(16, 1, 8), 256, 0, stream>>>(P, vT, partH, nullptr, nullptr, 1.f,
        512, 2048, 2048, 128, 16, 4, 2048ll * 2048, 128ll * 2048, 262144);
    reduce_pv<<<512, 256, 0, stream>>>(partH, head);
    // h += head @ Wdsum^T + bd
    gemm_bt<1><<<dim3(256, 1, 1), 256, 0, stream>>>(head, Wdst, h, nullptr, bd, 1.f,
        64, 128, 64, 1024, 32, 1, 0, 0, 0);
    ln_k<<<4096, 256, 0, stream>>>(h, g2, be2, z);
    // mid = relu(z2 @ W1 + c1) (bf16)
    gemm_bt<3><<<dim3(1024, 1, 1), 256, 0, stream>>>(z, W1t, nullptr, mid, c1, 1.f,
        1024, 1024, 1024, 4096, 32, 1, 0, 0, 0);
    // partF[sp] = mid @ W2^T (split-K x2, K=2048 each)
    gemm_bt<0><<<dim3(256, 1, 2), 256, 0, stream>>>(mid, W2t, partF, nullptr, nullptr, 1.f,
        2048, 4096, 4096, 1024, 32, 2, 0, 0, 4194304);
    reduce_ffn2<<<4096, 256, 0, stream>>>(partF, h, c2);
  }
  cast_k<<<4096, 256, 0, stream>>>(h, z);
  // out = hb @ Wfc + bfc
  gemm_bt<0><<<dim3(8000, 1, 1), 256, 0, stream>>>(z, Wfct, out, nullptr, bfc, 1.f,
      1024, 1024, 1024, 32000, 32, 1, 0, 0, 0);
}

// Round 3
// 2306.931 us; speedup vs baseline: 1.2346x; 1.0466x over previous
//
#include <hip/hip_runtime.h>

typedef unsigned short u16;
typedef __attribute__((ext_vector_type(4))) float f32x4;
typedef __attribute__((ext_vector_type(8))) __bf16 bf16x8;
typedef __attribute__((ext_vector_type(4))) unsigned short u16x4;

static __device__ __forceinline__ u16 f2bf(float f) {
  union { float f; unsigned u; } v; v.f = f;
  unsigned r = v.u + 0x7fffu + ((v.u >> 16) & 1u);
  return (u16)(r >> 16);
}

#define GLD_LDS(g, l) __builtin_amdgcn_global_load_lds( \
    (const __attribute__((address_space(1))) void*)(g), \
    (__attribute__((address_space(3))) void*)(l), 16, 0, 0)

// C = A[M,K] @ Bt[N,K]^T, bf16 in, f32 accum. 128x128 tile, BK=32, 4 waves.
// Grid: x = mtiles*ntiles flattened; bijective XCD chunk swizzle; grouped order:
//   groups of gm mt-tiles sweep all nt (B-panel reuse = gm blocks, A-group stays hot).
//   gm == mtiles reproduces plain M-major order.
// z = batch*nsplit+sp. A += batch*sA + sp*K ; B += batch*sB + sp*K ; C base = z*sC.
// EPI: 0 = Cf = alpha*acc + bias; 1 = Cf += acc + bias; 2 = Cb = bf16(acc+bias);
//      3 = Cb = bf16(relu(acc+bias)); 4 = EPI0 with nontemporal store (never-re-read C)
template<int EPI>
__global__ __launch_bounds__(256)
void gemm_bt(const u16* __restrict__ A, const u16* __restrict__ B,
             float* __restrict__ Cf, u16* __restrict__ Cb,
             const float* __restrict__ bias, float alpha,
             int K, int lda, int ldb, int ldc, int mtiles, int gm, int nsplit,
             long long sA, long long sB, long long sC)
{
  __shared__ u16 ldsA[128 * 32];
  __shared__ u16 ldsB[128 * 32];
  const int t = threadIdx.x;
  const int w = t >> 6, l = t & 63;

  // bijective XCD chunk swizzle (m204)
  int wg = blockIdx.x;
  const int nwg = gridDim.x;
  {
    const int q = nwg >> 3, r = nwg & 7;
    const int xcd = wg & 7, loc = wg >> 3;
    wg = (xcd < r ? xcd * (q + 1) : r * (q + 1) + (xcd - r) * q) + loc;
  }
  // grouped tile order: within group gi (gm mt's), nt advances, mtl fastest
  const int ntiles = nwg / mtiles;
  const int gsz = gm * ntiles;
  const int gi = wg / gsz;
  const int rr = wg - gi * gsz;
  const int nt = rr / gm;
  const int mt = gi * gm + (rr - nt * gm);
  const int m0 = mt << 7, n0 = nt << 7;

  const int bzRaw = blockIdx.z;
  int batch = bzRaw, sp = 0;
  if (nsplit > 1) { batch = bzRaw / nsplit; sp = bzRaw - batch * nsplit; }
  const u16* Ab = A + (long long)batch * sA + (long long)sp * K;
  const u16* Bb = B + (long long)batch * sB + (long long)sp * K;
  const long long cbase = (long long)bzRaw * sC;

  const int wr = (w >> 1) << 6, wc = (w & 1) << 6;
  const int l15 = l & 15, l16 = l >> 4;
  f32x4 acc[4][4] = {};

  for (int k0 = 0; k0 < K; k0 += 32) {
#pragma unroll
    for (int r = 0; r < 2; ++r) {
      const int o = (r << 12) + (t << 4);   // byte offset within the 8 KB tile
      const int row = o >> 6;               // 64 B per tile row (32 bf16)
      const int cole = (o & 63) >> 1;       // element col within BK
      GLD_LDS(Ab + (long long)(m0 + row) * lda + k0 + cole, &ldsA[(r << 11) + (w << 9)]);
      GLD_LDS(Bb + (long long)(n0 + row) * ldb + k0 + cole, &ldsB[(r << 11) + (w << 9)]);
    }
    __syncthreads();
    bf16x8 af[4], bg[4];
#pragma unroll
    for (int i = 0; i < 4; ++i) {
      af[i] = *(const bf16x8*)&ldsA[(wr + i * 16 + l15) * 32 + l16 * 8];
      bg[i] = *(const bf16x8*)&ldsB[(wc + i * 16 + l15) * 32 + l16 * 8];
    }
#pragma unroll
    for (int i = 0; i < 4; ++i)
#pragma unroll
      for (int j = 0; j < 4; ++j)
        acc[i][j] = __builtin_amdgcn_mfma_f32_16x16x32_bf16(af[i], bg[j], acc[i][j], 0, 0, 0);
    __syncthreads();
  }

#pragma unroll
  for (int i = 0; i < 4; ++i) {
    const int rbase = m0 + wr + i * 16 + l16 * 4;
#pragma unroll
    for (int j = 0; j < 4; ++j) {
      const int col = n0 + wc + j * 16 + l15;
      const float bv = bias ? bias[col] : 0.f;
#pragma unroll
      for (int r = 0; r < 4; ++r) {
        const long long idx = cbase + (long long)(rbase + r) * ldc + col;
        const float v = acc[i][j][r];
        if (EPI == 0)      Cf[idx] = alpha * v + bv;
        else if (EPI == 1) Cf[idx] += v + bv;
        else if (EPI == 2) Cb[idx] = f2bf(v + bv);
        else if (EPI == 3) { float x = v + bv; Cb[idx] = f2bf(x > 0.f ? x : 0.f); }
        else               __builtin_nontemporal_store(alpha * v + bv, &Cf[idx]);
      }
    }
  }
}

// LayerNorm over rows of 1024 f32 -> bf16 out
__global__ __launch_bounds__(256)
void ln_k(const float* __restrict__ x, const float* __restrict__ g,
          const float* __restrict__ b, u16* __restrict__ z)
{
  const long long row = blockIdx.x;
  f32x4 v = ((const f32x4*)(x + row * 1024))[threadIdx.x];
  float s = v[0] + v[1] + v[2] + v[3];
  float q = v[0] * v[0] + v[1] * v[1] + v[2] * v[2] + v[3] * v[3];
#pragma unroll
  for (int o = 32; o; o >>= 1) { s += __shfl_down(s, o); q += __shfl_down(q, o); }
  __shared__ float rs_[4], rq_[4];
  const int l = threadIdx.x & 63, w = threadIdx.x >> 6;
  if (l == 0) { rs_[w] = s; rq_[w] = q; }
  __syncthreads();
  s = rs_[0] + rs_[1] + rs_[2] + rs_[3];
  q = rq_[0] + rq_[1] + rq_[2] + rq_[3];
  const float mu = s * (1.f / 1024.f);
  const float rstd = rsqrtf(q * (1.f / 1024.f) - mu * mu + 1e-5f);
  const f32x4 gv = ((const f32x4*)g)[threadIdx.x];
  const f32x4 bv = ((const f32x4*)b)[threadIdx.x];
  u16x4 o4;
#pragma unroll
  for (int e = 0; e < 4; ++e) o4[e] = f2bf((v[e] - mu) * rstd * gv[e] + bv[e]);
  ((u16x4*)(z + row * 1024))[threadIdx.x] = o4;
}

// fused: hnew = h + p0 + p1 + c2 ; MODE0: h=hnew, z=LN(hnew)*g+b ; MODE1: z=bf16(hnew) (h dead)
template<int MODE>
__global__ __launch_bounds__(256)
void reduce_ln_k(const float* __restrict__ p, float* __restrict__ h,
                 const float* __restrict__ c2, const float* __restrict__ g,
                 const float* __restrict__ b, u16* __restrict__ z)
{
  const long long row = blockIdx.x;
  const int t = threadIdx.x;
  const long long i4 = (row << 8) + t;
  f32x4 v = ((const f32x4*)h)[i4]
          + ((const f32x4*)p)[i4] + ((const f32x4*)p)[i4 + 1048576]
          + ((const f32x4*)c2)[t];
  u16x4 o4;
  if (MODE == 1) {
#pragma unroll
    for (int e = 0; e < 4; ++e) o4[e] = f2bf(v[e]);
  } else {
    ((f32x4*)h)[i4] = v;
    float s = v[0] + v[1] + v[2] + v[3];
    float q = v[0] * v[0] + v[1] * v[1] + v[2] * v[2] + v[3] * v[3];
#pragma unroll
    for (int o = 32; o; o >>= 1) { s += __shfl_down(s, o); q += __shfl_down(q, o); }
    __shared__ float rs_[4], rq_[4];
    const int l = t & 63, w = t >> 6;
    if (l == 0) { rs_[w] = s; rq_[w] = q; }
    __syncthreads();
    s = rs_[0] + rs_[1] + rs_[2] + rs_[3];
    q = rq_[0] + rq_[1] + rq_[2] + rq_[3];
    const float mu = s * (1.f / 1024.f);
    const float rstd = rsqrtf(q * (1.f / 1024.f) - mu * mu + 1e-5f);
    const f32x4 gv = ((const f32x4*)g)[t];
    const f32x4 bv = ((const f32x4*)b)[t];
#pragma unroll
    for (int e = 0; e < 4; ++e) o4[e] = f2bf((v[e] - mu) * rstd * gv[e] + bv[e]);
  }
  ((u16x4*)z)[i4] = o4;
}

// row softmax over 2048 f32 -> bf16
__global__ __launch_bounds__(256)
void softmax_k(const float* __restrict__ S, u16* __restrict__ P)
{
  const long long row = blockIdx.x;
  const f32x4* sr = (const f32x4*)(S + row * 2048);
  f32x4 v0 = sr[threadIdx.x], v1 = sr[threadIdx.x + 256];
  float m = v0[0];
#pragma unroll
  for (int e = 1; e < 4; ++e) m = fmaxf(m, v0[e]);
#pragma unroll
  for (int e = 0; e < 4; ++e) m = fmaxf(m, v1[e]);
#pragma unroll
  for (int o = 32; o; o >>= 1) m = fmaxf(m, __shfl_down(m, o));
  __shared__ float rm[4], rs[4];
  const int l = threadIdx.x & 63, w = threadIdx.x >> 6;
  if (l == 0) rm[w] = m;
  __syncthreads();
  m = fmaxf(fmaxf(rm[0], rm[1]), fmaxf(rm[2], rm[3]));
  float e0[4], e1[4], s = 0.f;
#pragma unroll
  for (int e = 0; e < 4; ++e) { e0[e] = __expf(v0[e] - m); s += e0[e]; }
#pragma unroll
  for (int e = 0; e < 4; ++e) { e1[e] = __expf(v1[e] - m); s += e1[e]; }
#pragma unroll
  for (int o = 32; o; o >>= 1) s += __shfl_down(s, o);
  if (l == 0) rs[w] = s;
  __syncthreads();
  s = rs[0] + rs[1] + rs[2] + rs[3];
  const float inv = 1.f / s;
  u16x4 o0, o1;
#pragma unroll
  for (int e = 0; e < 4; ++e) { o0[e] = f2bf(e0[e] * inv); o1[e] = f2bf(e1[e] * inv); }
  ((u16x4*)(P + row * 2048))[threadIdx.x] = o0;
  ((u16x4*)(P + row * 2048))[threadIdx.x + 256] = o1;
}

__global__ __launch_bounds__(256)
void gather_k(const int* __restrict__ x, const float* __restrict__ emb, float* __restrict__ h)
{
  const long long tok = blockIdx.x;
  const long long r = (long long)x[tok] << 8;   // float4 units per row = 256
  ((f32x4*)h)[(tok << 8) + threadIdx.x] = ((const f32x4*)emb)[r + threadIdx.x];
}

// f32 [R][C] -> bf16 [C][R]
__global__ __launch_bounds__(256)
void tcast_k(const float* __restrict__ in, u16* __restrict__ out, int R, int C)
{
  __shared__ float tile[32][33];
  const int tx = threadIdx.x & 31, ty = threadIdx.x >> 5;
  const long long r0 = (long long)blockIdx.y << 5, c0 = (long long)blockIdx.x << 5;
#pragma unroll
  for (int yy = 0; yy < 32; yy += 8)
    tile[ty + yy][tx] = in[(r0 + ty + yy) * C + c0 + tx];
  __syncthreads();
#pragma unroll
  for (int yy = 0; yy < 32; yy += 8)
    out[(c0 + ty + yy) * R + r0 + tx] = f2bf(tile[tx][ty + yy]);
}

// fused QKV weight, transposed+padded: out[n][e], n in [0,256)
__global__ __launch_bounds__(256)
void wqkv_k(const float* __restrict__ Wq, const float* __restrict__ Wk,
            const float* __restrict__ Wv, u16* __restrict__ o)
{
  const int n = blockIdx.y;
  const long long e = (long long)blockIdx.x * 256 + threadIdx.x;
  float v = 0.f;
  if (n < 64)       v = Wq[e * 64 + n];
  else if (n < 128) v = Wk[e * 64 + (n - 64)];
  else if (n < 192) v = Wv[e * 64 + (n - 128)];
  o[(long long)n * 1024 + e] = f2bf(v);
}

__global__ __launch_bounds__(256)
void bqkv_k(const float* __restrict__ bq, const float* __restrict__ bk,
            const float* __restrict__ bv, float* __restrict__ o)
{
  const int n = threadIdx.x;
  float v = 0.f;
  if (n < 64)       v = bq[n];
  else if (n < 128) v = bk[n - 64];
  else if (n < 192) v = bv[n - 128];
  o[n] = v;
}

// Wdsum_t[e][a] = bf16( sum_h Wd[h*64+a][e] )   (i = e*64+a)
__global__ __launch_bounds__(256)
void wdsum_k(const float* __restrict__ Wd, u16* __restrict__ o)
{
  const int i = blockIdx.x * 256 + threadIdx.x;
  const int a = i & 63, e = i >> 6;
  float s = 0.f;
#pragma unroll
  for (int hh = 0; hh < 16; ++hh) s += Wd[(long long)(hh * 64 + a) * 1024 + e];
  o[i] = f2bf(s);
}

// head = bf16(sum of 4 partials) ; p layout [b*4+sp][2048*128]
__global__ __launch_bounds__(256)
void reduce_pv(const float* __restrict__ p, u16* __restrict__ head)
{
  const long long i4 = (long long)blockIdx.x * 256 + threadIdx.x;  // total 131072
  const long long b = i4 >> 16, loc = i4 & 65535;
  const long long base = b * 4 * 65536 + loc;
  const f32x4* p4 = (const f32x4*)p;
  f32x4 s = p4[base] + p4[base + 65536] + p4[base + 2 * 65536] + p4[base + 3 * 65536];
  u16x4 o;
#pragma unroll
  for (int e = 0; e < 4; ++e) o[e] = f2bf(s[e]);
  ((u16x4*)head)[i4] = o;
}

// qkv = bf16(p0+p1+bqkv), plus vT scatter for v-cols [128,192)
__global__ __launch_bounds__(256)
void reduce_qkv(const float* __restrict__ p, const float* __restrict__ bqkv,
                u16* __restrict__ qkv, u16* __restrict__ vT)
{
  const long long i4 = (long long)blockIdx.x * 256 + threadIdx.x;  // total 262144
  const int c4 = (int)(i4 & 63);
  const long long row = i4 >> 6;
  f32x4 s = ((const f32x4*)p)[i4] + ((const f32x4*)p)[i4 + 262144]
          + ((const f32x4*)bqkv)[c4];
  u16x4 o;
#pragma unroll
  for (int e = 0; e < 4; ++e) o[e] = f2bf(s[e]);
  ((u16x4*)qkv)[i4] = o;
  if (c4 >= 32 && c4 < 48) {  // v columns 128..191
    const long long b = row >> 11, sidx = row & 2047;
#pragma unroll
    for (int e = 0; e < 4; ++e) {
      const int a = (c4 - 32) * 4 + e;
      vT[(b * 128 + a) * 2048 + sidx] = o[e];
    }
  }
}

extern "C" void kernel_launch(void* const* d_in, const int* in_sizes, int n_in,
                              void* d_out, int out_size, void* d_ws, size_t ws_size,
                              hipStream_t stream) {
  const int*   x   = (const int*)d_in[0];
  const float* emb = (const float*)d_in[1];
  const float* Wq  = (const float*)d_in[2];
  const float* bq  = (const float*)d_in[3];
  const float* Wk  = (const float*)d_in[4];
  const float* bk  = (const float*)d_in[5];
  const float* Wv  = (const float*)d_in[6];
  const float* bv  = (const float*)d_in[7];
  const float* Wd  = (const float*)d_in[8];
  const float* bd  = (const float*)d_in[9];
  const float* g1  = (const float*)d_in[10];
  const float* be1 = (const float*)d_in[11];
  const float* g2  = (const float*)d_in[12];
  const float* be2 = (const float*)d_in[13];
  const float* W1  = (const float*)d_in[14];
  const float* c1  = (const float*)d_in[15];
  const float* W2  = (const float*)d_in[16];
  const float* c2  = (const float*)d_in[17];
  const float* Wfc = (const float*)d_in[18];
  const float* bfc = (const float*)d_in[19];
  float* out = (float*)d_out;

  char* ws = (char*)d_ws;
  size_t off = 0;
  auto alloc = [&](size_t bytes) { void* p = ws + off; off = (off + bytes + 255) & ~(size_t)255; return p; };
  float*  h     = (float*) alloc(4096ull * 1024 * 4);
  u16*    z     = (u16*)   alloc(4096ull * 1024 * 2);   // z1/z2/hb (reused)
  u16*    qkv   = (u16*)   alloc(4096ull * 256 * 2);
  u16*    vT    = (u16*)   alloc(2ull * 128 * 2048 * 2);
  u16*    head  = (u16*)   alloc(2ull * 2048 * 128 * 2);
  u16*    mid   = (u16*)   alloc(4096ull * 4096 * 2);
  // scratch region with lifetime-based aliasing:
  //   partQ (8.4MB) [QKV gemm -> reduce]   at SCR+0
  //   sc    (33.5MB)[scores  -> softmax]   at SCR+0      (partQ dead)
  //   P     (16.8MB)[softmax -> PV gemm]   at SCR+33.5MB
  //   partH (8.4MB) [PV gemm -> reduce]    at SCR+0      (sc dead)
  //   partF (33.5MB)[FFN2    -> reduce]    at SCR+0      (P dead)
  char*   SCR   = (char*)  alloc(2ull * 2048 * 2048 * 4 + 2ull * 2048 * 2048 * 2);
  float*  sc    = (float*)SCR;
  float*  partQ = (float*)SCR;
  float*  partH = (float*)SCR;
  float*  partF = (float*)SCR;
  u16*    P     = (u16*)(SCR + 2ull * 2048 * 2048 * 4);
  u16*    Wqkvt = (u16*)   alloc(256ull * 1024 * 2);
  float*  bqkv  = (float*) alloc(256 * 4);
  u16*    Wdst  = (u16*)   alloc(1024ull * 64 * 2);
  u16*    W1t   = (u16*)   alloc(4096ull * 1024 * 2);
  u16*    W2t   = (u16*)   alloc(1024ull * 4096 * 2);
  u16*    Wfct  = (u16*)   alloc(32000ull * 1024 * 2);

  // ---- prep (every launch; no caching allowed) ----
  gather_k<<<4096, 256, 0, stream>>>(x, emb, h);
  wqkv_k<<<dim3(4, 256), 256, 0, stream>>>(Wq, Wk, Wv, Wqkvt);
  bqkv_k<<<1, 256, 0, stream>>>(bq, bk, bv, bqkv);
  wdsum_k<<<256, 256, 0, stream>>>(Wd, Wdst);
  tcast_k<<<dim3(128, 32), 256, 0, stream>>>(W1, W1t, 1024, 4096);
  tcast_k<<<dim3(32, 128), 256, 0, stream>>>(W2, W2t, 4096, 1024);
  tcast_k<<<dim3(1000, 32), 256, 0, stream>>>(Wfc, Wfct, 1024, 32000);

  for (int layer = 0; layer < 8; ++layer) {
    if (layer == 0)
      ln_k<<<4096, 256, 0, stream>>>(h, g1, be1, z);
    // partQ[z] = z1 @ Wqkv^T (split-K x2, K=512 each)
    gemm_bt<0><<<dim3(64, 1, 2), 256, 0, stream>>>(z, Wqkvt, partQ, nullptr, nullptr, 1.f,
        512, 1024, 1024, 256, 32, 32, 2, 0, 0, 1048576);
    reduce_qkv<<<1024, 256, 0, stream>>>(partQ, bqkv, qkv, vT);
    // scores[b] = 0.125 * q @ k^T
    gemm_bt<0><<<dim3(256, 1, 2), 256, 0, stream>>>(qkv, qkv + 64, sc, nullptr, nullptr, 0.125f,
        64, 256, 256, 2048, 16, 16, 1, 2048ll * 256, 2048ll * 256, 2048ll * 2048);
    softmax_k<<<4096, 256, 0, stream>>>(sc, P);
    // partH[b*4+sp] = P @ vT^T (split-K x4, K=512 each)
    gemm_bt<0><<<dim3(16, 1, 8), 256, 0, stream>>>(P, vT, partH, nullptr, nullptr, 1.f,
        512, 2048, 2048, 128, 16, 16, 4, 2048ll * 2048, 128ll * 2048, 262144);
    reduce_pv<<<512, 256, 0, stream>>>(partH, head);
    // h += head @ Wdsum^T + bd
    gemm_bt<1><<<dim3(256, 1, 1), 256, 0, stream>>>(head, Wdst, h, nullptr, bd, 1.f,
        64, 128, 64, 1024, 32, 32, 1, 0, 0, 0);
    ln_k<<<4096, 256, 0, stream>>>(h, g2, be2, z);
    // mid = relu(z2 @ W1 + c1) (bf16)
    gemm_bt<3><<<dim3(1024, 1, 1), 256, 0, stream>>>(z, W1t, nullptr, mid, c1, 1.f,
        1024, 1024, 1024, 4096, 32, 32, 1, 0, 0, 0);
    // partF[sp] = mid @ W2^T (split-K x2, K=2048 each)
    gemm_bt<0><<<dim3(256, 1, 2), 256, 0, stream>>>(mid, W2t, partF, nullptr, nullptr, 1.f,
        2048, 4096, 4096, 1024, 32, 32, 2, 0, 0, 4194304);
    // fused: h += partF0+partF1+c2 ; z = LN(h) (layers 0-6) or bf16(h) (layer 7)
    if (layer < 7)
      reduce_ln_k<0><<<4096, 256, 0, stream>>>(partF, h, c2, g1, be1, z);
    else
      reduce_ln_k<1><<<4096, 256, 0, stream>>>(partF, h, c2, nullptr, nullptr, z);
  }
  // out = hb @ Wfc + bfc  (grouped gm=16, nontemporal C stores)
  gemm_bt<4><<<dim3(8000, 1, 1), 256, 0, stream>>>(z, Wfct, out, nullptr, bfc, 1.f,
      1024, 1024, 1024, 32000, 32, 16, 1, 0, 0, 0);
}

// Round 4
// 2289.399 us; speedup vs baseline: 1.2441x; 1.0077x over previous
//
#include <hip/hip_runtime.h>

typedef unsigned short u16;
typedef __attribute__((ext_vector_type(4))) float f32x4;
typedef __attribute__((ext_vector_type(8))) __bf16 bf16x8;
typedef __attribute__((ext_vector_type(4))) unsigned short u16x4;

static __device__ __forceinline__ u16 f2bf(float f) {
  union { float f; unsigned u; } v; v.f = f;
  unsigned r = v.u + 0x7fffu + ((v.u >> 16) & 1u);
  return (u16)(r >> 16);
}

#define GLD_LDS(g, l) __builtin_amdgcn_global_load_lds( \
    (const __attribute__((address_space(1))) void*)(g), \
    (__attribute__((address_space(3))) void*)(l), 16, 0, 0)

// C = A[M,K] @ Bt[N,K]^T, bf16 in, f32 accum. 128x128 tile, BK=32, 4 waves.
// Grid: x = mtiles*ntiles flattened; bijective XCD chunk swizzle; grouped order
// (groups of gm mt-tiles sweep all nt). z = batch*nsplit+sp.
// EPI: 0 = Cf = alpha*acc + bias; 1 = Cf += acc + bias; 2 = Cb = bf16(acc+bias);
//      3 = Cb = bf16(relu(acc+bias))
template<int EPI>
__global__ __launch_bounds__(256)
void gemm_bt(const u16* __restrict__ A, const u16* __restrict__ B,
             float* __restrict__ Cf, u16* __restrict__ Cb,
             const float* __restrict__ bias, float alpha,
             int K, int lda, int ldb, int ldc, int mtiles, int gm, int nsplit,
             long long sA, long long sB, long long sC)
{
  __shared__ u16 ldsA[128 * 32];
  __shared__ u16 ldsB[128 * 32];
  const int t = threadIdx.x;
  const int w = t >> 6, l = t & 63;

  int wg = blockIdx.x;
  const int nwg = gridDim.x;
  {
    const int q = nwg >> 3, r = nwg & 7;
    const int xcd = wg & 7, loc = wg >> 3;
    wg = (xcd < r ? xcd * (q + 1) : r * (q + 1) + (xcd - r) * q) + loc;
  }
  const int ntiles = nwg / mtiles;
  const int gsz = gm * ntiles;
  const int gi = wg / gsz;
  const int rr = wg - gi * gsz;
  const int nt = rr / gm;
  const int mt = gi * gm + (rr - nt * gm);
  const int m0 = mt << 7, n0 = nt << 7;

  const int bzRaw = blockIdx.z;
  int batch = bzRaw, sp = 0;
  if (nsplit > 1) { batch = bzRaw / nsplit; sp = bzRaw - batch * nsplit; }
  const u16* Ab = A + (long long)batch * sA + (long long)sp * K;
  const u16* Bb = B + (long long)batch * sB + (long long)sp * K;
  const long long cbase = (long long)bzRaw * sC;

  const int wr = (w >> 1) << 6, wc = (w & 1) << 6;
  const int l15 = l & 15, l16 = l >> 4;
  f32x4 acc[4][4] = {};

  for (int k0 = 0; k0 < K; k0 += 32) {
#pragma unroll
    for (int r = 0; r < 2; ++r) {
      const int o = (r << 12) + (t << 4);
      const int row = o >> 6;
      const int cole = (o & 63) >> 1;
      GLD_LDS(Ab + (long long)(m0 + row) * lda + k0 + cole, &ldsA[(r << 11) + (w << 9)]);
      GLD_LDS(Bb + (long long)(n0 + row) * ldb + k0 + cole, &ldsB[(r << 11) + (w << 9)]);
    }
    __syncthreads();
    bf16x8 af[4], bg[4];
#pragma unroll
    for (int i = 0; i < 4; ++i) {
      af[i] = *(const bf16x8*)&ldsA[(wr + i * 16 + l15) * 32 + l16 * 8];
      bg[i] = *(const bf16x8*)&ldsB[(wc + i * 16 + l15) * 32 + l16 * 8];
    }
#pragma unroll
    for (int i = 0; i < 4; ++i)
#pragma unroll
      for (int j = 0; j < 4; ++j)
        acc[i][j] = __builtin_amdgcn_mfma_f32_16x16x32_bf16(af[i], bg[j], acc[i][j], 0, 0, 0);
    __syncthreads();
  }

#pragma unroll
  for (int i = 0; i < 4; ++i) {
    const int rbase = m0 + wr + i * 16 + l16 * 4;
#pragma unroll
    for (int j = 0; j < 4; ++j) {
      const int col = n0 + wc + j * 16 + l15;
      const float bv = bias ? bias[col] : 0.f;
#pragma unroll
      for (int r = 0; r < 4; ++r) {
        const long long idx = cbase + (long long)(rbase + r) * ldc + col;
        const float v = acc[i][j][r];
        if (EPI == 0)      Cf[idx] = alpha * v + bv;
        else if (EPI == 1) Cf[idx] += v + bv;
        else if (EPI == 2) Cb[idx] = f2bf(v + bv);
        else               { float x = v + bv; Cb[idx] = f2bf(x > 0.f ? x : 0.f); }
      }
    }
  }
}

// ---------------- fused flash attention ----------------
// 1 wave per 16 q-rows. D=64, S=2048, no mask, scale=0.125.
// qkv[b*2048+s][256]: q=cols0-63, k=64-127 ; vT[b*64+d][2048].
// head[b*2048+s][64] bf16 out.
__device__ __forceinline__ void fstep(
    const bf16x8 (&ck)[4][2], const bf16x8 (&cv)[4][2],
    bf16x8 (&nk)[4][2], bf16x8 (&nv)[4][2],
    const bf16x8 (&qf)[2], float (&m)[4], float (&ls)[4], f32x4 (&o)[4],
    const u16* qb, const u16* vb, int kv0, int kvn, u16* pl, int l15, int l16)
{
  f32x4 s[4] = {};
#pragma unroll
  for (int ni = 0; ni < 4; ++ni)
#pragma unroll
    for (int kk = 0; kk < 2; ++kk)
      s[ni] = __builtin_amdgcn_mfma_f32_16x16x32_bf16(qf[kk], ck[ni][kk], s[ni], 0, 0, 0);
  // prefetch next K tile
#pragma unroll
  for (int ni = 0; ni < 4; ++ni)
#pragma unroll
    for (int kk = 0; kk < 2; ++kk)
      nk[ni][kk] = *(const bf16x8*)(qb + (kvn + ni * 16 + l15) * 256 + 64 + kk * 32 + l16 * 8);
#pragma unroll
  for (int ni = 0; ni < 4; ++ni) s[ni] *= 0.125f;
  float al[4], ps[4];
#pragma unroll
  for (int r = 0; r < 4; ++r) {
    float v = fmaxf(fmaxf(s[0][r], s[1][r]), fmaxf(s[2][r], s[3][r]));
    v = fmaxf(v, __shfl_xor(v, 1)); v = fmaxf(v, __shfl_xor(v, 2));
    v = fmaxf(v, __shfl_xor(v, 4)); v = fmaxf(v, __shfl_xor(v, 8));
    const float mn = fmaxf(m[r], v);
    al[r] = __expf(m[r] - mn);
    m[r] = mn;
    ps[r] = 0.f;
  }
#pragma unroll
  for (int ni = 0; ni < 4; ++ni)
#pragma unroll
    for (int r = 0; r < 4; ++r) {
      const float p = __expf(s[ni][r] - m[r]);
      ps[r] += p;
      pl[(l16 * 4 + r) * 72 + ni * 16 + l15] = f2bf(p);
    }
#pragma unroll
  for (int r = 0; r < 4; ++r) {
    float t = ps[r];
    t += __shfl_xor(t, 1); t += __shfl_xor(t, 2);
    t += __shfl_xor(t, 4); t += __shfl_xor(t, 8);
    ls[r] = ls[r] * al[r] + t;
  }
#pragma unroll
  for (int nd = 0; nd < 4; ++nd)
#pragma unroll
    for (int r = 0; r < 4; ++r) o[nd][r] *= al[r];
  bf16x8 pa[2];
#pragma unroll
  for (int kk = 0; kk < 2; ++kk)
    pa[kk] = *(const bf16x8*)&pl[l15 * 72 + kk * 32 + l16 * 8];
#pragma unroll
  for (int nd = 0; nd < 4; ++nd)
#pragma unroll
    for (int kk = 0; kk < 2; ++kk)
      o[nd] = __builtin_amdgcn_mfma_f32_16x16x32_bf16(pa[kk], cv[nd][kk], o[nd], 0, 0, 0);
  // prefetch next V tile
#pragma unroll
  for (int nd = 0; nd < 4; ++nd)
#pragma unroll
    for (int kk = 0; kk < 2; ++kk)
      nv[nd][kk] = *(const bf16x8*)(vb + (nd * 16 + l15) * 2048 + kvn + kk * 32 + l16 * 8);
  (void)kv0;
}

__global__ __launch_bounds__(64)
void flash_k(const u16* __restrict__ qkv, const u16* __restrict__ vT,
             u16* __restrict__ head)
{
  __shared__ u16 pl[16 * 72];
  const int l = threadIdx.x, l15 = l & 15, l16 = l >> 4;
  const int b = blockIdx.x >> 7, q0 = (blockIdx.x & 127) << 4;
  const u16* qb = qkv + (long long)b * 2048 * 256;
  const u16* vb = vT + (long long)b * 64 * 2048;
  bf16x8 qf[2];
#pragma unroll
  for (int kk = 0; kk < 2; ++kk)
    qf[kk] = *(const bf16x8*)(qb + (q0 + l15) * 256 + kk * 32 + l16 * 8);
  float m[4], ls[4];
  f32x4 o[4] = {};
#pragma unroll
  for (int r = 0; r < 4; ++r) { m[r] = -1e30f; ls[r] = 0.f; }
  bf16x8 ka[4][2], va[4][2], kb[4][2], vb2[4][2];
#pragma unroll
  for (int ni = 0; ni < 4; ++ni)
#pragma unroll
    for (int kk = 0; kk < 2; ++kk) {
      ka[ni][kk] = *(const bf16x8*)(qb + (ni * 16 + l15) * 256 + 64 + kk * 32 + l16 * 8);
      va[ni][kk] = *(const bf16x8*)(vb + (ni * 16 + l15) * 2048 + kk * 32 + l16 * 8);
    }
  for (int t = 0; t < 32; t += 2) {
    fstep(ka, va, kb, vb2, qf, m, ls, o, qb, vb, t * 64, (t + 1) * 64, pl, l15, l16);
    fstep(kb, vb2, ka, va, qf, m, ls, o, qb, vb, (t + 1) * 64,
          (t + 2 < 32 ? (t + 2) * 64 : 31 * 64), pl, l15, l16);
  }
#pragma unroll
  for (int nd = 0; nd < 4; ++nd)
#pragma unroll
    for (int r = 0; r < 4; ++r)
      head[((long long)b * 2048 + q0 + l16 * 4 + r) * 64 + nd * 16 + l15] =
          f2bf(o[nd][r] / ls[r]);
}

// LayerNorm over rows of 1024 f32 -> bf16 out
__global__ __launch_bounds__(256)
void ln_k(const float* __restrict__ x, const float* __restrict__ g,
          const float* __restrict__ b, u16* __restrict__ z)
{
  const long long row = blockIdx.x;
  f32x4 v = ((const f32x4*)(x + row * 1024))[threadIdx.x];
  float s = v[0] + v[1] + v[2] + v[3];
  float q = v[0] * v[0] + v[1] * v[1] + v[2] * v[2] + v[3] * v[3];
#pragma unroll
  for (int o = 32; o; o >>= 1) { s += __shfl_down(s, o); q += __shfl_down(q, o); }
  __shared__ float rs_[4], rq_[4];
  const int l = threadIdx.x & 63, w = threadIdx.x >> 6;
  if (l == 0) { rs_[w] = s; rq_[w] = q; }
  __syncthreads();
  s = rs_[0] + rs_[1] + rs_[2] + rs_[3];
  q = rq_[0] + rq_[1] + rq_[2] + rq_[3];
  const float mu = s * (1.f / 1024.f);
  const float rstd = rsqrtf(q * (1.f / 1024.f) - mu * mu + 1e-5f);
  const f32x4 gv = ((const f32x4*)g)[threadIdx.x];
  const f32x4 bv = ((const f32x4*)b)[threadIdx.x];
  u16x4 o4;
#pragma unroll
  for (int e = 0; e < 4; ++e) o4[e] = f2bf((v[e] - mu) * rstd * gv[e] + bv[e]);
  ((u16x4*)(z + row * 1024))[threadIdx.x] = o4;
}

// fused: hnew = h + p0 + p1 + c2 ; MODE0: h=hnew, z=LN(hnew)*g+b ; MODE1: z=bf16(hnew)
template<int MODE>
__global__ __launch_bounds__(256)
void reduce_ln_k(const float* __restrict__ p, float* __restrict__ h,
                 const float* __restrict__ c2, const float* __restrict__ g,
                 const float* __restrict__ b, u16* __restrict__ z)
{
  const long long row = blockIdx.x;
  const int t = threadIdx.x;
  const long long i4 = (row << 8) + t;
  f32x4 v = ((const f32x4*)h)[i4]
          + ((const f32x4*)p)[i4] + ((const f32x4*)p)[i4 + 1048576]
          + ((const f32x4*)c2)[t];
  u16x4 o4;
  if (MODE == 1) {
#pragma unroll
    for (int e = 0; e < 4; ++e) o4[e] = f2bf(v[e]);
  } else {
    ((f32x4*)h)[i4] = v;
    float s = v[0] + v[1] + v[2] + v[3];
    float q = v[0] * v[0] + v[1] * v[1] + v[2] * v[2] + v[3] * v[3];
#pragma unroll
    for (int o = 32; o; o >>= 1) { s += __shfl_down(s, o); q += __shfl_down(q, o); }
    __shared__ float rs_[4], rq_[4];
    const int l = t & 63, w = t >> 6;
    if (l == 0) { rs_[w] = s; rq_[w] = q; }
    __syncthreads();
    s = rs_[0] + rs_[1] + rs_[2] + rs_[3];
    q = rq_[0] + rq_[1] + rq_[2] + rq_[3];
    const float mu = s * (1.f / 1024.f);
    const float rstd = rsqrtf(q * (1.f / 1024.f) - mu * mu + 1e-5f);
    const f32x4 gv = ((const f32x4*)g)[t];
    const f32x4 bv = ((const f32x4*)b)[t];
#pragma unroll
    for (int e = 0; e < 4; ++e) o4[e] = f2bf((v[e] - mu) * rstd * gv[e] + bv[e]);
  }
  ((u16x4*)z)[i4] = o4;
}

__global__ __launch_bounds__(256)
void gather_k(const int* __restrict__ x, const float* __restrict__ emb, float* __restrict__ h)
{
  const long long tok = blockIdx.x;
  const long long r = (long long)x[tok] << 8;
  ((f32x4*)h)[(tok << 8) + threadIdx.x] = ((const f32x4*)emb)[r + threadIdx.x];
}

// f32 [R][C] -> bf16 [C][R]
__global__ __launch_bounds__(256)
void tcast_k(const float* __restrict__ in, u16* __restrict__ out, int R, int C)
{
  __shared__ float tile[32][33];
  const int tx = threadIdx.x & 31, ty = threadIdx.x >> 5;
  const long long r0 = (long long)blockIdx.y << 5, c0 = (long long)blockIdx.x << 5;
#pragma unroll
  for (int yy = 0; yy < 32; yy += 8)
    tile[ty + yy][tx] = in[(r0 + ty + yy) * C + c0 + tx];
  __syncthreads();
#pragma unroll
  for (int yy = 0; yy < 32; yy += 8)
    out[(c0 + ty + yy) * R + r0 + tx] = f2bf(tile[tx][ty + yy]);
}

__global__ __launch_bounds__(256)
void wqkv_k(const float* __restrict__ Wq, const float* __restrict__ Wk,
            const float* __restrict__ Wv, u16* __restrict__ o)
{
  const int n = blockIdx.y;
  const long long e = (long long)blockIdx.x * 256 + threadIdx.x;
  float v = 0.f;
  if (n < 64)       v = Wq[e * 64 + n];
  else if (n < 128) v = Wk[e * 64 + (n - 64)];
  else if (n < 192) v = Wv[e * 64 + (n - 128)];
  o[(long long)n * 1024 + e] = f2bf(v);
}

__global__ __launch_bounds__(256)
void bqkv_k(const float* __restrict__ bq, const float* __restrict__ bk,
            const float* __restrict__ bv, float* __restrict__ o)
{
  const int n = threadIdx.x;
  float v = 0.f;
  if (n < 64)       v = bq[n];
  else if (n < 128) v = bk[n - 64];
  else if (n < 192) v = bv[n - 128];
  o[n] = v;
}

// Wdsum_t[e][a] = bf16( sum_h Wd[h*64+a][e] )
__global__ __launch_bounds__(256)
void wdsum_k(const float* __restrict__ Wd, u16* __restrict__ o)
{
  const int i = blockIdx.x * 256 + threadIdx.x;
  const int a = i & 63, e = i >> 6;
  float s = 0.f;
#pragma unroll
  for (int hh = 0; hh < 16; ++hh) s += Wd[(long long)(hh * 64 + a) * 1024 + e];
  o[i] = f2bf(s);
}

// qkv = bf16(p0+p1+bqkv), plus vT scatter for v-cols [128,192) -> vT[b*64+a][2048]
__global__ __launch_bounds__(256)
void reduce_qkv(const float* __restrict__ p, const float* __restrict__ bqkv,
                u16* __restrict__ qkv, u16* __restrict__ vT)
{
  const long long i4 = (long long)blockIdx.x * 256 + threadIdx.x;  // total 262144
  const int c4 = (int)(i4 & 63);
  const long long row = i4 >> 6;
  f32x4 s = ((const f32x4*)p)[i4] + ((const f32x4*)p)[i4 + 262144]
          + ((const f32x4*)bqkv)[c4];
  u16x4 o;
#pragma unroll
  for (int e = 0; e < 4; ++e) o[e] = f2bf(s[e]);
  ((u16x4*)qkv)[i4] = o;
  if (c4 >= 32 && c4 < 48) {  // v columns 128..191 -> a = 0..63
    const long long b = row >> 11, sidx = row & 2047;
#pragma unroll
    for (int e = 0; e < 4; ++e) {
      const int a = (c4 - 32) * 4 + e;
      vT[(b * 64 + a) * 2048 + sidx] = o[e];
    }
  }
}

extern "C" void kernel_launch(void* const* d_in, const int* in_sizes, int n_in,
                              void* d_out, int out_size, void* d_ws, size_t ws_size,
                              hipStream_t stream) {
  const int*   x   = (const int*)d_in[0];
  const float* emb = (const float*)d_in[1];
  const float* Wq  = (const float*)d_in[2];
  const float* bq  = (const float*)d_in[3];
  const float* Wk  = (const float*)d_in[4];
  const float* bk  = (const float*)d_in[5];
  const float* Wv  = (const float*)d_in[6];
  const float* bv  = (const float*)d_in[7];
  const float* Wd  = (const float*)d_in[8];
  const float* bd  = (const float*)d_in[9];
  const float* g1  = (const float*)d_in[10];
  const float* be1 = (const float*)d_in[11];
  const float* g2  = (const float*)d_in[12];
  const float* be2 = (const float*)d_in[13];
  const float* W1  = (const float*)d_in[14];
  const float* c1  = (const float*)d_in[15];
  const float* W2  = (const float*)d_in[16];
  const float* c2  = (const float*)d_in[17];
  const float* Wfc = (const float*)d_in[18];
  const float* bfc = (const float*)d_in[19];
  float* out = (float*)d_out;

  char* ws = (char*)d_ws;
  size_t off = 0;
  auto alloc = [&](size_t bytes) { void* p = ws + off; off = (off + bytes + 255) & ~(size_t)255; return p; };
  float*  h     = (float*) alloc(4096ull * 1024 * 4);
  u16*    z     = (u16*)   alloc(4096ull * 1024 * 2);   // z1/z2/hb (reused)
  u16*    qkv   = (u16*)   alloc(4096ull * 256 * 2);
  u16*    vT    = (u16*)   alloc(2ull * 64 * 2048 * 2);
  u16*    head  = (u16*)   alloc(4096ull * 64 * 2);
  u16*    mid   = (u16*)   alloc(4096ull * 4096 * 2);
  // scratch: partQ (8.4MB) and partF (33.5MB) never live simultaneously
  char*   SCR   = (char*)  alloc(2ull * 4096 * 1024 * 4);
  float*  partQ = (float*)SCR;
  float*  partF = (float*)SCR;
  u16*    Wqkvt = (u16*)   alloc(256ull * 1024 * 2);
  float*  bqkv  = (float*) alloc(256 * 4);
  u16*    Wdst  = (u16*)   alloc(1024ull * 64 * 2);
  u16*    W1t   = (u16*)   alloc(4096ull * 1024 * 2);
  u16*    W2t   = (u16*)   alloc(1024ull * 4096 * 2);
  u16*    Wfct  = (u16*)   alloc(32000ull * 1024 * 2);

  // ---- prep (every launch; no caching allowed) ----
  gather_k<<<4096, 256, 0, stream>>>(x, emb, h);
  wqkv_k<<<dim3(4, 256), 256, 0, stream>>>(Wq, Wk, Wv, Wqkvt);
  bqkv_k<<<1, 256, 0, stream>>>(bq, bk, bv, bqkv);
  wdsum_k<<<256, 256, 0, stream>>>(Wd, Wdst);
  tcast_k<<<dim3(128, 32), 256, 0, stream>>>(W1, W1t, 1024, 4096);
  tcast_k<<<dim3(32, 128), 256, 0, stream>>>(W2, W2t, 4096, 1024);
  tcast_k<<<dim3(1000, 32), 256, 0, stream>>>(Wfc, Wfct, 1024, 32000);

  for (int layer = 0; layer < 8; ++layer) {
    if (layer == 0)
      ln_k<<<4096, 256, 0, stream>>>(h, g1, be1, z);
    // partQ[z] = z1 @ Wqkv^T (split-K x2, K=512 each)
    gemm_bt<0><<<dim3(64, 1, 2), 256, 0, stream>>>(z, Wqkvt, partQ, nullptr, nullptr, 1.f,
        512, 1024, 1024, 256, 32, 32, 2, 0, 0, 1048576);
    reduce_qkv<<<1024, 256, 0, stream>>>(partQ, bqkv, qkv, vT);
    // fused attention: head = softmax(0.125 * q k^T) v
    flash_k<<<256, 64, 0, stream>>>(qkv, vT, head);
    // h += head @ Wdsum^T + bd
    gemm_bt<1><<<dim3(256, 1, 1), 256, 0, stream>>>(head, Wdst, h, nullptr, bd, 1.f,
        64, 64, 64, 1024, 32, 32, 1, 0, 0, 0);
    ln_k<<<4096, 256, 0, stream>>>(h, g2, be2, z);
    // mid = relu(z2 @ W1 + c1) (bf16)
    gemm_bt<3><<<dim3(1024, 1, 1), 256, 0, stream>>>(z, W1t, nullptr, mid, c1, 1.f,
        1024, 1024, 1024, 4096, 32, 32, 1, 0, 0, 0);
    // partF[sp] = mid @ W2^T (split-K x2, K=2048 each)
    gemm_bt<0><<<dim3(256, 1, 2), 256, 0, stream>>>(mid, W2t, partF, nullptr, nullptr, 1.f,
        2048, 4096, 4096, 1024, 32, 32, 2, 0, 0, 4194304);
    // fused: h += partF0+partF1+c2 ; z = LN(h) (layers 0-6) or bf16(h) (layer 7)
    if (layer < 7)
      reduce_ln_k<0><<<4096, 256, 0, stream>>>(partF, h, c2, g1, be1, z);
    else
      reduce_ln_k<1><<<4096, 256, 0, stream>>>(partF, h, c2, nullptr, nullptr, z);
  }
  // out = hb @ Wfc + bfc  (grouped gm=16)
  gemm_bt<0><<<dim3(8000, 1, 1), 256, 0, stream>>>(z, Wfct, out, nullptr, bfc, 1.f,
      1024, 1024, 1024, 32000, 32, 16, 1, 0, 0, 0);
}

// Round 5
// 1759.370 us; speedup vs baseline: 1.6189x; 1.3013x over previous
//
#include <hip/hip_runtime.h>

typedef unsigned short u16;
typedef __attribute__((ext_vector_type(4))) float f32x4;
typedef __attribute__((ext_vector_type(8))) __bf16 bf16x8;
typedef __attribute__((ext_vector_type(4))) unsigned short u16x4;

static __device__ __forceinline__ u16 f2bf(float f) {
  union { float f; unsigned u; } v; v.f = f;
  unsigned r = v.u + 0x7fffu + ((v.u >> 16) & 1u);
  return (u16)(r >> 16);
}

#define GLD_LDS(g, l) __builtin_amdgcn_global_load_lds( \
    (const __attribute__((address_space(1))) void*)(g), \
    (__attribute__((address_space(3))) void*)(l), 16, 0, 0)

// ---------------------------------------------------------------------------
// 256x256-tile BK=64 8-wave GEMM (T2 swizzle + T4 counted vmcnt + T5 setprio).
// C = A[M,K] @ Bt[N,K]^T. 512 threads, waves 2M x 4N, per-wave out 128x64.
// LDS: 2 dbuf x (A 256x64 + B 256x64) bf16 = 128 KB (dynamic).
// Swizzle: data(row, col8) stored at 16B-slot col8^(row&7)  (pre-swizzled
// global source + swizzled ds_read; LDS dest stays linear - rule #21).
// Pipeline: prologue stages kt0,kt1; iter kt waits vmcnt(8) (kt's 8 loads
// done, kt+1's 8 in flight), computes, mid-barrier after lgkmcnt(0), then
// stages kt+2 into the just-read buffer. vmcnt(0) only on the last iter.
// EPI: 0 = Cf = alpha*acc + bias; 2 = Cb = bf16(acc+bias); 3 = bf16 relu.
// ---------------------------------------------------------------------------
template<int EPI>
__global__ __launch_bounds__(512, 2)
void gemm8p(const u16* __restrict__ A, const u16* __restrict__ B,
            float* __restrict__ Cf, u16* __restrict__ Cb,
            const float* __restrict__ bias, float alpha,
            int K, int lda, int ldb, int ldc, int mtiles, int gm, int nsplit,
            long long sA, long long sB, long long sC)
{
  extern __shared__ u16 lds8[];
  const int t = threadIdx.x;
  const int w = t >> 6, l = t & 63;
  const int l15 = l & 15, l16 = l >> 4;
  const int wr = w >> 2, wc = w & 3;

  int wg = blockIdx.x;
  const int nwg = gridDim.x;
  {
    const int q = nwg >> 3, r = nwg & 7;
    const int xcd = wg & 7, loc = wg >> 3;
    wg = (xcd < r ? xcd * (q + 1) : r * (q + 1) + (xcd - r) * q) + loc;
  }
  const int ntiles = nwg / mtiles;
  const int gsz = gm * ntiles;
  const int gi = wg / gsz;
  const int rr = wg - gi * gsz;
  const int nt = rr / gm;
  const int mt = gi * gm + (rr - nt * gm);
  const int m0 = mt << 8, n0 = nt << 8;

  const int bz = blockIdx.z;
  int batch = bz, sp = 0;
  if (nsplit > 1) { batch = bz / nsplit; sp = bz - batch * nsplit; }
  const u16* Ab = A + (long long)batch * sA + (long long)sp * K;
  const u16* Bb = B + (long long)batch * sB + (long long)sp * K;
  const long long cbase = (long long)bz * sC;

  // staging: 8 gload_lds/thread per K-tile (4 A + 4 B), 16B each.
  // thread t covers row i*64 + (t>>3), 16B-unit (t&7) pre-swizzled by row&7.
  const int srow = t >> 3;
  const int scol = (((t & 7) ^ (srow & 7)) << 3);
  const u16* gA[4]; const u16* gB[4];
#pragma unroll
  for (int i = 0; i < 4; ++i) {
    gA[i] = Ab + (long long)(m0 + i * 64 + srow) * lda + scol;
    gB[i] = Bb + (long long)(n0 + i * 64 + srow) * ldb + scol;
  }
  const int ldst = w << 9;  // wave-uniform elem offset (w*1024 B)

  auto STAGE = [&](int buf) {
#pragma unroll
    for (int i = 0; i < 4; ++i) {
      GLD_LDS(gA[i], &lds8[buf * 16384 + i * 4096 + ldst]);
      gA[i] += 64;
    }
#pragma unroll
    for (int i = 0; i < 4; ++i) {
      GLD_LDS(gB[i], &lds8[32768 + buf * 16384 + i * 4096 + ldst]);
      gB[i] += 64;
    }
  };

  STAGE(0);
  STAGE(1);

  f32x4 acc[8][4] = {};
  const int nkt = K >> 6;
  const int aRow = wr * 128 + l15;
  const int bRow = wc * 64 + l15;
  const int swz = l15 & 7;

  for (int kt = 0; kt < nkt; ++kt) {
    const int buf = kt & 1;
    if (kt < nkt - 1) asm volatile("s_waitcnt vmcnt(8)" ::: "memory");
    else              asm volatile("s_waitcnt vmcnt(0)" ::: "memory");
    __builtin_amdgcn_s_barrier();
    __builtin_amdgcn_sched_barrier(0);

    const int abase = buf * 16384;
    const int bbase = 32768 + buf * 16384;
    bf16x8 af[4][2], bf[4][2];
#pragma unroll
    for (int mf = 0; mf < 4; ++mf)
#pragma unroll
      for (int kk = 0; kk < 2; ++kk)
        af[mf][kk] = *(const bf16x8*)&lds8[abase + (aRow + mf * 16) * 64 + ((((kk << 2) + l16)) ^ swz) * 8];
#pragma unroll
    for (int nf = 0; nf < 4; ++nf)
#pragma unroll
      for (int kk = 0; kk < 2; ++kk)
        bf[nf][kk] = *(const bf16x8*)&lds8[bbase + (bRow + nf * 16) * 64 + ((((kk << 2) + l16)) ^ swz) * 8];

    __builtin_amdgcn_s_setprio(1);
#pragma unroll
    for (int mf = 0; mf < 4; ++mf)
#pragma unroll
      for (int nf = 0; nf < 4; ++nf)
#pragma unroll
        for (int kk = 0; kk < 2; ++kk)
          acc[mf][nf] = __builtin_amdgcn_mfma_f32_16x16x32_bf16(af[mf][kk], bf[nf][kk], acc[mf][nf], 0, 0, 0);
    __builtin_amdgcn_s_setprio(0);

    bf16x8 ah[4][2];
#pragma unroll
    for (int mf = 0; mf < 4; ++mf)
#pragma unroll
      for (int kk = 0; kk < 2; ++kk)
        ah[mf][kk] = *(const bf16x8*)&lds8[abase + (aRow + 64 + mf * 16) * 64 + ((((kk << 2) + l16)) ^ swz) * 8];

    // all this iteration's LDS reads sampled -> safe to overwrite buf
    asm volatile("s_waitcnt lgkmcnt(0)" ::: "memory");
    __builtin_amdgcn_s_barrier();
    __builtin_amdgcn_sched_barrier(0);
    if (kt + 2 < nkt) STAGE(buf);

    __builtin_amdgcn_s_setprio(1);
#pragma unroll
    for (int mf = 0; mf < 4; ++mf)
#pragma unroll
      for (int nf = 0; nf < 4; ++nf)
#pragma unroll
        for (int kk = 0; kk < 2; ++kk)
          acc[mf + 4][nf] = __builtin_amdgcn_mfma_f32_16x16x32_bf16(ah[mf][kk], bf[nf][kk], acc[mf + 4][nf], 0, 0, 0);
    __builtin_amdgcn_s_setprio(0);
  }

#pragma unroll
  for (int mf = 0; mf < 8; ++mf) {
    const int rbase = m0 + wr * 128 + mf * 16 + l16 * 4;
#pragma unroll
    for (int nf = 0; nf < 4; ++nf) {
      const int col = n0 + wc * 64 + nf * 16 + l15;
      const float bv = bias ? bias[col] : 0.f;
#pragma unroll
      for (int r = 0; r < 4; ++r) {
        const long long idx = cbase + (long long)(rbase + r) * ldc + col;
        const float v = acc[mf][nf][r];
        if (EPI == 0)      Cf[idx] = alpha * v + bv;
        else if (EPI == 2) Cb[idx] = f2bf(v + bv);
        else               { float x = v + bv; Cb[idx] = f2bf(x > 0.f ? x : 0.f); }
      }
    }
  }
}

// ---- legacy 128x128 engine (small shapes: QKV, headWd) ----
template<int EPI>
__global__ __launch_bounds__(256)
void gemm_bt(const u16* __restrict__ A, const u16* __restrict__ B,
             float* __restrict__ Cf, u16* __restrict__ Cb,
             const float* __restrict__ bias, float alpha,
             int K, int lda, int ldb, int ldc, int mtiles, int gm, int nsplit,
             long long sA, long long sB, long long sC)
{
  __shared__ u16 ldsA[128 * 32];
  __shared__ u16 ldsB[128 * 32];
  const int t = threadIdx.x;
  const int w = t >> 6, l = t & 63;

  int wg = blockIdx.x;
  const int nwg = gridDim.x;
  {
    const int q = nwg >> 3, r = nwg & 7;
    const int xcd = wg & 7, loc = wg >> 3;
    wg = (xcd < r ? xcd * (q + 1) : r * (q + 1) + (xcd - r) * q) + loc;
  }
  const int ntiles = nwg / mtiles;
  const int gsz = gm * ntiles;
  const int gi = wg / gsz;
  const int rr = wg - gi * gsz;
  const int nt = rr / gm;
  const int mt = gi * gm + (rr - nt * gm);
  const int m0 = mt << 7, n0 = nt << 7;

  const int bzRaw = blockIdx.z;
  int batch = bzRaw, sp = 0;
  if (nsplit > 1) { batch = bzRaw / nsplit; sp = bzRaw - batch * nsplit; }
  const u16* Ab = A + (long long)batch * sA + (long long)sp * K;
  const u16* Bb = B + (long long)batch * sB + (long long)sp * K;
  const long long cbase = (long long)bzRaw * sC;

  const int wr = (w >> 1) << 6, wc = (w & 1) << 6;
  const int l15 = l & 15, l16 = l >> 4;
  f32x4 acc[4][4] = {};

  for (int k0 = 0; k0 < K; k0 += 32) {
#pragma unroll
    for (int r = 0; r < 2; ++r) {
      const int o = (r << 12) + (t << 4);
      const int row = o >> 6;
      const int cole = (o & 63) >> 1;
      GLD_LDS(Ab + (long long)(m0 + row) * lda + k0 + cole, &ldsA[(r << 11) + (w << 9)]);
      GLD_LDS(Bb + (long long)(n0 + row) * ldb + k0 + cole, &ldsB[(r << 11) + (w << 9)]);
    }
    __syncthreads();
    bf16x8 af[4], bg[4];
#pragma unroll
    for (int i = 0; i < 4; ++i) {
      af[i] = *(const bf16x8*)&ldsA[(wr + i * 16 + l15) * 32 + l16 * 8];
      bg[i] = *(const bf16x8*)&ldsB[(wc + i * 16 + l15) * 32 + l16 * 8];
    }
#pragma unroll
    for (int i = 0; i < 4; ++i)
#pragma unroll
      for (int j = 0; j < 4; ++j)
        acc[i][j] = __builtin_amdgcn_mfma_f32_16x16x32_bf16(af[i], bg[j], acc[i][j], 0, 0, 0);
    __syncthreads();
  }

#pragma unroll
  for (int i = 0; i < 4; ++i) {
    const int rbase = m0 + wr + i * 16 + l16 * 4;
#pragma unroll
    for (int j = 0; j < 4; ++j) {
      const int col = n0 + wc + j * 16 + l15;
      const float bv = bias ? bias[col] : 0.f;
#pragma unroll
      for (int r = 0; r < 4; ++r) {
        const long long idx = cbase + (long long)(rbase + r) * ldc + col;
        const float v = acc[i][j][r];
        if (EPI == 0)      Cf[idx] = alpha * v + bv;
        else if (EPI == 1) Cf[idx] += v + bv;
        else if (EPI == 2) Cb[idx] = f2bf(v + bv);
        else               { float x = v + bv; Cb[idx] = f2bf(x > 0.f ? x : 0.f); }
      }
    }
  }
}

// ---------------- fused flash attention ----------------
__device__ __forceinline__ void fstep(
    const bf16x8 (&ck)[4][2], const bf16x8 (&cv)[4][2],
    bf16x8 (&nk)[4][2], bf16x8 (&nv)[4][2],
    const bf16x8 (&qf)[2], float (&m)[4], float (&ls)[4], f32x4 (&o)[4],
    const u16* qb, const u16* vb, int kv0, int kvn, u16* pl, int l15, int l16)
{
  f32x4 s[4] = {};
#pragma unroll
  for (int ni = 0; ni < 4; ++ni)
#pragma unroll
    for (int kk = 0; kk < 2; ++kk)
      s[ni] = __builtin_amdgcn_mfma_f32_16x16x32_bf16(qf[kk], ck[ni][kk], s[ni], 0, 0, 0);
#pragma unroll
  for (int ni = 0; ni < 4; ++ni)
#pragma unroll
    for (int kk = 0; kk < 2; ++kk)
      nk[ni][kk] = *(const bf16x8*)(qb + (kvn + ni * 16 + l15) * 256 + 64 + kk * 32 + l16 * 8);
#pragma unroll
  for (int ni = 0; ni < 4; ++ni) s[ni] *= 0.125f;
  float al[4], ps[4];
#pragma unroll
  for (int r = 0; r < 4; ++r) {
    float v = fmaxf(fmaxf(s[0][r], s[1][r]), fmaxf(s[2][r], s[3][r]));
    v = fmaxf(v, __shfl_xor(v, 1)); v = fmaxf(v, __shfl_xor(v, 2));
    v = fmaxf(v, __shfl_xor(v, 4)); v = fmaxf(v, __shfl_xor(v, 8));
    const float mn = fmaxf(m[r], v);
    al[r] = __expf(m[r] - mn);
    m[r] = mn;
    ps[r] = 0.f;
  }
#pragma unroll
  for (int ni = 0; ni < 4; ++ni)
#pragma unroll
    for (int r = 0; r < 4; ++r) {
      const float p = __expf(s[ni][r] - m[r]);
      ps[r] += p;
      pl[(l16 * 4 + r) * 72 + ni * 16 + l15] = f2bf(p);
    }
#pragma unroll
  for (int r = 0; r < 4; ++r) {
    float t = ps[r];
    t += __shfl_xor(t, 1); t += __shfl_xor(t, 2);
    t += __shfl_xor(t, 4); t += __shfl_xor(t, 8);
    ls[r] = ls[r] * al[r] + t;
  }
#pragma unroll
  for (int nd = 0; nd < 4; ++nd)
#pragma unroll
    for (int r = 0; r < 4; ++r) o[nd][r] *= al[r];
  bf16x8 pa[2];
#pragma unroll
  for (int kk = 0; kk < 2; ++kk)
    pa[kk] = *(const bf16x8*)&pl[l15 * 72 + kk * 32 + l16 * 8];
#pragma unroll
  for (int nd = 0; nd < 4; ++nd)
#pragma unroll
    for (int kk = 0; kk < 2; ++kk)
      o[nd] = __builtin_amdgcn_mfma_f32_16x16x32_bf16(pa[kk], cv[nd][kk], o[nd], 0, 0, 0);
#pragma unroll
  for (int nd = 0; nd < 4; ++nd)
#pragma unroll
    for (int kk = 0; kk < 2; ++kk)
      nv[nd][kk] = *(const bf16x8*)(vb + (nd * 16 + l15) * 2048 + kvn + kk * 32 + l16 * 8);
  (void)kv0;
}

__global__ __launch_bounds__(64)
void flash_k(const u16* __restrict__ qkv, const u16* __restrict__ vT,
             u16* __restrict__ head)
{
  __shared__ u16 pl[16 * 72];
  const int l = threadIdx.x, l15 = l & 15, l16 = l >> 4;
  const int b = blockIdx.x >> 7, q0 = (blockIdx.x & 127) << 4;
  const u16* qb = qkv + (long long)b * 2048 * 256;
  const u16* vb = vT + (long long)b * 64 * 2048;
  bf16x8 qf[2];
#pragma unroll
  for (int kk = 0; kk < 2; ++kk)
    qf[kk] = *(const bf16x8*)(qb + (q0 + l15) * 256 + kk * 32 + l16 * 8);
  float m[4], ls[4];
  f32x4 o[4] = {};
#pragma unroll
  for (int r = 0; r < 4; ++r) { m[r] = -1e30f; ls[r] = 0.f; }
  bf16x8 ka[4][2], va[4][2], kb[4][2], vb2[4][2];
#pragma unroll
  for (int ni = 0; ni < 4; ++ni)
#pragma unroll
    for (int kk = 0; kk < 2; ++kk) {
      ka[ni][kk] = *(const bf16x8*)(qb + (ni * 16 + l15) * 256 + 64 + kk * 32 + l16 * 8);
      va[ni][kk] = *(const bf16x8*)(vb + (ni * 16 + l15) * 2048 + kk * 32 + l16 * 8);
    }
  for (int t = 0; t < 32; t += 2) {
    fstep(ka, va, kb, vb2, qf, m, ls, o, qb, vb, t * 64, (t + 1) * 64, pl, l15, l16);
    fstep(kb, vb2, ka, va, qf, m, ls, o, qb, vb, (t + 1) * 64,
          (t + 2 < 32 ? (t + 2) * 64 : 31 * 64), pl, l15, l16);
  }
#pragma unroll
  for (int nd = 0; nd < 4; ++nd)
#pragma unroll
    for (int r = 0; r < 4; ++r)
      head[((long long)b * 2048 + q0 + l16 * 4 + r) * 64 + nd * 16 + l15] =
          f2bf(o[nd][r] / ls[r]);
}

// LayerNorm over rows of 1024 f32 -> bf16 out
__global__ __launch_bounds__(256)
void ln_k(const float* __restrict__ x, const float* __restrict__ g,
          const float* __restrict__ b, u16* __restrict__ z)
{
  const long long row = blockIdx.x;
  f32x4 v = ((const f32x4*)(x + row * 1024))[threadIdx.x];
  float s = v[0] + v[1] + v[2] + v[3];
  float q = v[0] * v[0] + v[1] * v[1] + v[2] * v[2] + v[3] * v[3];
#pragma unroll
  for (int o = 32; o; o >>= 1) { s += __shfl_down(s, o); q += __shfl_down(q, o); }
  __shared__ float rs_[4], rq_[4];
  const int l = threadIdx.x & 63, w = threadIdx.x >> 6;
  if (l == 0) { rs_[w] = s; rq_[w] = q; }
  __syncthreads();
  s = rs_[0] + rs_[1] + rs_[2] + rs_[3];
  q = rq_[0] + rq_[1] + rq_[2] + rq_[3];
  const float mu = s * (1.f / 1024.f);
  const float rstd = rsqrtf(q * (1.f / 1024.f) - mu * mu + 1e-5f);
  const f32x4 gv = ((const f32x4*)g)[threadIdx.x];
  const f32x4 bv = ((const f32x4*)b)[threadIdx.x];
  u16x4 o4;
#pragma unroll
  for (int e = 0; e < 4; ++e) o4[e] = f2bf((v[e] - mu) * rstd * gv[e] + bv[e]);
  ((u16x4*)(z + row * 1024))[threadIdx.x] = o4;
}

// fused: hnew = h + sum_{s<4} bf16partial_s + c2 ; MODE0: h=hnew, z=LN(hnew);
// MODE1: z=bf16(hnew) (h dead)
template<int MODE>
__global__ __launch_bounds__(256)
void reduce_ln_k(const u16* __restrict__ p, float* __restrict__ h,
                 const float* __restrict__ c2, const float* __restrict__ g,
                 const float* __restrict__ b, u16* __restrict__ z)
{
  const long long row = blockIdx.x;
  const int t = threadIdx.x;
  const long long i4 = (row << 8) + t;
  f32x4 v = ((const f32x4*)h)[i4] + ((const f32x4*)c2)[t];
#pragma unroll
  for (int s = 0; s < 4; ++s) {
    u16x4 pv = ((const u16x4*)p)[i4 + (long long)s * 1048576];
#pragma unroll
    for (int e = 0; e < 4; ++e) {
      union { unsigned u; float f; } x; x.u = ((unsigned)pv[e]) << 16;
      v[e] += x.f;
    }
  }
  u16x4 o4;
  if (MODE == 1) {
#pragma unroll
    for (int e = 0; e < 4; ++e) o4[e] = f2bf(v[e]);
  } else {
    ((f32x4*)h)[i4] = v;
    float s = v[0] + v[1] + v[2] + v[3];
    float q = v[0] * v[0] + v[1] * v[1] + v[2] * v[2] + v[3] * v[3];
#pragma unroll
    for (int o = 32; o; o >>= 1) { s += __shfl_down(s, o); q += __shfl_down(q, o); }
    __shared__ float rs_[4], rq_[4];
    const int l = t & 63, w = t >> 6;
    if (l == 0) { rs_[w] = s; rq_[w] = q; }
    __syncthreads();
    s = rs_[0] + rs_[1] + rs_[2] + rs_[3];
    q = rq_[0] + rq_[1] + rq_[2] + rq_[3];
    const float mu = s * (1.f / 1024.f);
    const float rstd = rsqrtf(q * (1.f / 1024.f) - mu * mu + 1e-5f);
    const f32x4 gv = ((const f32x4*)g)[t];
    const f32x4 bv = ((const f32x4*)b)[t];
#pragma unroll
    for (int e = 0; e < 4; ++e) o4[e] = f2bf((v[e] - mu) * rstd * gv[e] + bv[e]);
  }
  ((u16x4*)z)[i4] = o4;
}

__global__ __launch_bounds__(256)
void gather_k(const int* __restrict__ x, const float* __restrict__ emb, float* __restrict__ h)
{
  const long long tok = blockIdx.x;
  const long long r = (long long)x[tok] << 8;
  ((f32x4*)h)[(tok << 8) + threadIdx.x] = ((const f32x4*)emb)[r + threadIdx.x];
}

// f32 [R][C] -> bf16 [C][R]
__global__ __launch_bounds__(256)
void tcast_k(const float* __restrict__ in, u16* __restrict__ out, int R, int C)
{
  __shared__ float tile[32][33];
  const int tx = threadIdx.x & 31, ty = threadIdx.x >> 5;
  const long long r0 = (long long)blockIdx.y << 5, c0 = (long long)blockIdx.x << 5;
#pragma unroll
  for (int yy = 0; yy < 32; yy += 8)
    tile[ty + yy][tx] = in[(r0 + ty + yy) * C + c0 + tx];
  __syncthreads();
#pragma unroll
  for (int yy = 0; yy < 32; yy += 8)
    out[(c0 + ty + yy) * R + r0 + tx] = f2bf(tile[tx][ty + yy]);
}

__global__ __launch_bounds__(256)
void wqkv_k(const float* __restrict__ Wq, const float* __restrict__ Wk,
            const float* __restrict__ Wv, u16* __restrict__ o)
{
  const int n = blockIdx.y;
  const long long e = (long long)blockIdx.x * 256 + threadIdx.x;
  float v = 0.f;
  if (n < 64)       v = Wq[e * 64 + n];
  else if (n < 128) v = Wk[e * 64 + (n - 64)];
  else if (n < 192) v = Wv[e * 64 + (n - 128)];
  o[(long long)n * 1024 + e] = f2bf(v);
}

__global__ __launch_bounds__(256)
void bqkv_k(const float* __restrict__ bq, const float* __restrict__ bk,
            const float* __restrict__ bv, float* __restrict__ o)
{
  const int n = threadIdx.x;
  float v = 0.f;
  if (n < 64)       v = bq[n];
  else if (n < 128) v = bk[n - 64];
  else if (n < 192) v = bv[n - 128];
  o[n] = v;
}

__global__ __launch_bounds__(256)
void wdsum_k(const float* __restrict__ Wd, u16* __restrict__ o)
{
  const int i = blockIdx.x * 256 + threadIdx.x;
  const int a = i & 63, e = i >> 6;
  float s = 0.f;
#pragma unroll
  for (int hh = 0; hh < 16; ++hh) s += Wd[(long long)(hh * 64 + a) * 1024 + e];
  o[i] = f2bf(s);
}

// qkv = bf16(p0+p1+bqkv), plus vT scatter for v-cols [128,192) -> vT[b*64+a][2048]
__global__ __launch_bounds__(256)
void reduce_qkv(const float* __restrict__ p, const float* __restrict__ bqkv,
                u16* __restrict__ qkv, u16* __restrict__ vT)
{
  const long long i4 = (long long)blockIdx.x * 256 + threadIdx.x;
  const int c4 = (int)(i4 & 63);
  const long long row = i4 >> 6;
  f32x4 s = ((const f32x4*)p)[i4] + ((const f32x4*)p)[i4 + 262144]
          + ((const f32x4*)bqkv)[c4];
  u16x4 o;
#pragma unroll
  for (int e = 0; e < 4; ++e) o[e] = f2bf(s[e]);
  ((u16x4*)qkv)[i4] = o;
  if (c4 >= 32 && c4 < 48) {
    const long long b = row >> 11, sidx = row & 2047;
#pragma unroll
    for (int e = 0; e < 4; ++e) {
      const int a = (c4 - 32) * 4 + e;
      vT[(b * 64 + a) * 2048 + sidx] = o[e];
    }
  }
}

extern "C" void kernel_launch(void* const* d_in, const int* in_sizes, int n_in,
                              void* d_out, int out_size, void* d_ws, size_t ws_size,
                              hipStream_t stream) {
  const int*   x   = (const int*)d_in[0];
  const float* emb = (const float*)d_in[1];
  const float* Wq  = (const float*)d_in[2];
  const float* bq  = (const float*)d_in[3];
  const float* Wk  = (const float*)d_in[4];
  const float* bk  = (const float*)d_in[5];
  const float* Wv  = (const float*)d_in[6];
  const float* bv  = (const float*)d_in[7];
  const float* Wd  = (const float*)d_in[8];
  const float* bd  = (const float*)d_in[9];
  const float* g1  = (const float*)d_in[10];
  const float* be1 = (const float*)d_in[11];
  const float* g2  = (const float*)d_in[12];
  const float* be2 = (const float*)d_in[13];
  const float* W1  = (const float*)d_in[14];
  const float* c1  = (const float*)d_in[15];
  const float* W2  = (const float*)d_in[16];
  const float* c2  = (const float*)d_in[17];
  const float* Wfc = (const float*)d_in[18];
  const float* bfc = (const float*)d_in[19];
  float* out = (float*)d_out;

  // 128 KB dynamic LDS opt-in for the 256^2 engine (idempotent, per launch)
  hipFuncSetAttribute(reinterpret_cast<const void*>(gemm8p<0>),
                      hipFuncAttributeMaxDynamicSharedMemorySize, 131072);
  hipFuncSetAttribute(reinterpret_cast<const void*>(gemm8p<2>),
                      hipFuncAttributeMaxDynamicSharedMemorySize, 131072);
  hipFuncSetAttribute(reinterpret_cast<const void*>(gemm8p<3>),
                      hipFuncAttributeMaxDynamicSharedMemorySize, 131072);

  char* ws = (char*)d_ws;
  size_t off = 0;
  auto alloc = [&](size_t bytes) { void* p = ws + off; off = (off + bytes + 255) & ~(size_t)255; return p; };
  float*  h     = (float*) alloc(4096ull * 1024 * 4);
  u16*    z     = (u16*)   alloc(4096ull * 1024 * 2);
  u16*    qkv   = (u16*)   alloc(4096ull * 256 * 2);
  u16*    vT    = (u16*)   alloc(2ull * 64 * 2048 * 2);
  u16*    head  = (u16*)   alloc(4096ull * 64 * 2);
  u16*    mid   = (u16*)   alloc(4096ull * 4096 * 2);
  // scratch: partQ (8.4MB f32) and partF (33.5MB bf16 x4 splits) never coexist
  char*   SCR   = (char*)  alloc(2ull * 4096 * 1024 * 4);
  float*  partQ = (float*)SCR;
  u16*    partF = (u16*)SCR;
  u16*    Wqkvt = (u16*)   alloc(256ull * 1024 * 2);
  float*  bqkv  = (float*) alloc(256 * 4);
  u16*    Wdst  = (u16*)   alloc(1024ull * 64 * 2);
  u16*    W1t   = (u16*)   alloc(4096ull * 1024 * 2);
  u16*    W2t   = (u16*)   alloc(1024ull * 4096 * 2);
  u16*    Wfct  = (u16*)   alloc(32000ull * 1024 * 2);

  // ---- prep (every launch; no caching allowed) ----
  gather_k<<<4096, 256, 0, stream>>>(x, emb, h);
  wqkv_k<<<dim3(4, 256), 256, 0, stream>>>(Wq, Wk, Wv, Wqkvt);
  bqkv_k<<<1, 256, 0, stream>>>(bq, bk, bv, bqkv);
  wdsum_k<<<256, 256, 0, stream>>>(Wd, Wdst);
  tcast_k<<<dim3(128, 32), 256, 0, stream>>>(W1, W1t, 1024, 4096);
  tcast_k<<<dim3(32, 128), 256, 0, stream>>>(W2, W2t, 4096, 1024);
  tcast_k<<<dim3(1000, 32), 256, 0, stream>>>(Wfc, Wfct, 1024, 32000);

  for (int layer = 0; layer < 8; ++layer) {
    if (layer == 0)
      ln_k<<<4096, 256, 0, stream>>>(h, g1, be1, z);
    // partQ[z] = z1 @ Wqkv^T (split-K x2, K=512 each) -- legacy engine
    gemm_bt<0><<<dim3(64, 1, 2), 256, 0, stream>>>(z, Wqkvt, partQ, nullptr, nullptr, 1.f,
        512, 1024, 1024, 256, 32, 32, 2, 0, 0, 1048576);
    reduce_qkv<<<1024, 256, 0, stream>>>(partQ, bqkv, qkv, vT);
    // fused attention
    flash_k<<<256, 64, 0, stream>>>(qkv, vT, head);
    // h += head @ Wdsum^T + bd -- legacy engine
    gemm_bt<1><<<dim3(256, 1, 1), 256, 0, stream>>>(head, Wdst, h, nullptr, bd, 1.f,
        64, 64, 64, 1024, 32, 32, 1, 0, 0, 0);
    ln_k<<<4096, 256, 0, stream>>>(h, g2, be2, z);
    // mid = relu(z2 @ W1 + c1) -- 256^2 engine
    gemm8p<3><<<dim3(256, 1, 1), 512, 131072, stream>>>(z, W1t, nullptr, mid, c1, 1.f,
        1024, 1024, 1024, 4096, 16, 16, 1, 0, 0, 0);
    // partF[sp] = bf16(mid @ W2^T) (split-K x4, K=1024 each) -- 256^2 engine
    gemm8p<2><<<dim3(64, 1, 4), 512, 131072, stream>>>(mid, W2t, nullptr, partF, nullptr, 1.f,
        1024, 4096, 4096, 1024, 16, 16, 4, 0, 0, 4194304);
    // fused: h += sum(partF) + c2 ; z = LN(h) (layers 0-6) or bf16(h) (layer 7)
    if (layer < 7)
      reduce_ln_k<0><<<4096, 256, 0, stream>>>(partF, h, c2, g1, be1, z);
    else
      reduce_ln_k<1><<<4096, 256, 0, stream>>>(partF, h, c2, nullptr, nullptr, z);
  }
  // out = hb @ Wfc + bfc -- 256^2 engine, grouped gm=8
  gemm8p<0><<<dim3(2000, 1, 1), 512, 131072, stream>>>(z, Wfct, out, nullptr, bfc, 1.f,
      1024, 1024, 1024, 32000, 16, 8, 1, 0, 0, 0);
}